// Round 2
// baseline (419.831 us; speedup 1.0000x reference)
//
#include <hip/hip_runtime.h>
#include <stdint.h>

#define DN 128

typedef short s16x8 __attribute__((ext_vector_type(8)));
typedef float f32x4 __attribute__((ext_vector_type(4)));

__device__ __forceinline__ float bfs(unsigned short u){ return __uint_as_float(((uint32_t)u) << 16); }
__device__ __forceinline__ uint32_t f2bf(float f){
    uint32_t x = __float_as_uint(f);
    return (x + 0x7FFFu + ((x >> 16) & 1u)) >> 16;   // RTNE
}
__device__ __forceinline__ uint32_t packbf(float a, float b){ return f2bf(a) | (f2bf(b) << 16); }
__device__ __forceinline__ float tanh_(float x){
    float e = __expf(2.0f * x);
    return 1.0f - 2.0f / (e + 1.0f);
}

// ---------------- mask format detector: 1 = byte-packed bool, 0 = int32 ----
__global__ void k_detect(const uint32_t* mask, int nwords, int* flag){
    __shared__ int sh;
    if (threadIdx.x == 0) sh = 0;
    __syncthreads();
    int bad = 0;
    for (int i = threadIdx.x; i < nwords; i += blockDim.x)
        if (mask[i] > 1u) bad = 1;
    if (bad) atomicOr(&sh, 1);
    __syncthreads();
    if (threadIdx.x == 0) *flag = sh;
}

// ---------------- weight f32 -> bf16 pre-conversion ------------------------
struct WC { const float* src[6]; };
__global__ void k_wcvt(WC wc, unsigned short* dstp){
    int i = blockIdx.x * 256 + threadIdx.x;      // 6 * 16384 elements
    int m = i >> 14, o = i & 16383;
    dstp[(size_t)m * 16384 + o] = (unsigned short)f2bf(wc.src[m][o]);
}

// ---------------- CSR build ------------------------------------------------
__global__ void k_hist(const int* dst, int* counts, int E){
    int e = blockIdx.x * blockDim.x + threadIdx.x;
    if (e < E) atomicAdd(&counts[dst[e]], 1);
}
__global__ void k_scan_a(const int* counts, int* bsums){
    int t = threadIdx.x;
    int s = counts[blockIdx.x * 256 + t];
    #pragma unroll
    for (int o = 32; o; o >>= 1) s += __shfl_xor(s, o);
    __shared__ int wsum[4];
    if ((t & 63) == 0) wsum[t >> 6] = s;
    __syncthreads();
    if (t == 0) bsums[blockIdx.x] = wsum[0] + wsum[1] + wsum[2] + wsum[3];
}
__global__ void k_scan_b(int* bsums, int nb){
    __shared__ int buf[256];
    int t = threadIdx.x;
    int v = (t < nb) ? bsums[t] : 0;
    buf[t] = v; __syncthreads();
    for (int o = 1; o < 256; o <<= 1){
        int add = (t >= o) ? buf[t - o] : 0;
        __syncthreads();
        buf[t] += add;
        __syncthreads();
    }
    if (t < nb) bsums[t] = buf[t] - v;   // exclusive
}
__global__ void k_scan_c(const int* counts, const int* bsums, int* rowst, int* cursor, int npad, int E){
    __shared__ int buf[256];
    int t = threadIdx.x, i = blockIdx.x * 256 + t;
    int c = counts[i];
    buf[t] = c; __syncthreads();
    for (int o = 1; o < 256; o <<= 1){
        int add = (t >= o) ? buf[t - o] : 0;
        __syncthreads();
        buf[t] += add;
        __syncthreads();
    }
    int rsv = buf[t] - c + bsums[blockIdx.x];
    rowst[i] = rsv; cursor[i] = rsv;
    if (i == npad - 1) rowst[npad] = E;
}
__global__ void k_scatter(const int* dst, int* cursor, int* eord, int E){
    int e = blockIdx.x * blockDim.x + threadIdx.x;
    if (e < E){ int pos = atomicAdd(&cursor[dst[e]], 1); eord[pos] = e; }
}

// ---------------- per-node fused 3-layer online-softmax accumulation -------
// One wave per node. Lane holds elements 2*lane, 2*lane+1 of each D=128 row.
__global__ __launch_bounds__(256)
void k_node(const float2* ent2, const float2* rel2,
            const int* src, const int* etype,
            const unsigned char* mask8, const int* flagp,
            const int* rowst, const int* eord,
            uint32_t* Sw, float* Rv, int Nn, int npad)
{
    int t = threadIdx.x, lane = t & 63, wv = t >> 6;
    int v = blockIdx.x * 4 + wv;
    if (v >= npad) return;
    int bmode = *flagp;
    const int* mask32 = (const int*)mask8;

    float dx = 0.f, dy = 0.f; int deg = 0, rs = 0;
    if (v < Nn){
        rs = rowst[v]; deg = rowst[v + 1] - rs;
        float2 dw = ent2[(size_t)v * 64 + lane];
        dx = dw.x; dy = dw.y;
    }
    float m0=-1e30f, m1=-1e30f, m2=-1e30f;
    float si0=0,si1=0,si2=0, so0=0,so1=0,so2=0;
    float ai0x=0,ai0y=0,ao0x=0,ao0y=0;
    float ai1x=0,ai1y=0,ao1x=0,ao1y=0;
    float ai2x=0,ai2y=0,ao2x=0,ao2y=0;

    for (int base = 0; base < deg; base += 64){
        int nb = min(64, deg - base);
        int sv = 0, tv = 0, mk = 0;
        if (lane < nb){
            int eid = eord[rs + base + lane];
            sv = src[eid]; tv = etype[eid];
            mk = bmode ? (int)mask8[eid] : mask32[eid];
        }
        for (int j = 0; j < nb; ++j){
            int sj = __shfl(sv, j), tj = __shfl(tv, j), mj = __shfl(mk, j);
            float2 sw = ent2[(size_t)sj * 64 + lane];
            float2 rw = rel2[(size_t)tj * 64 + lane];
            float sx = sw.x, sy = sw.y, rx = rw.x, ry = rw.y;
            float cx = sx * rx, cy = sy * ry;
            float p0 = rx * dx + ry * dy;     // edge: rel . dst
            float p1 = sx * dx + sy * dy;     // node: src . dst
            float p2 = cx * dx + cy * dy;     // comp: (src*rel) . dst
            #pragma unroll
            for (int o = 32; o; o >>= 1){
                p0 += __shfl_xor(p0, o);
                p1 += __shfl_xor(p1, o);
                p2 += __shfl_xor(p2, o);
            }
            { float nm = fmaxf(m0, p0), f = __expf(m0 - nm), e = __expf(p0 - nm);
              si0*=f; so0*=f; ai0x*=f; ai0y*=f; ao0x*=f; ao0y*=f;
              if (mj){ si0+=e; ai0x+=e*rx; ai0y+=e*ry; } else { so0+=e; ao0x+=e*rx; ao0y+=e*ry; }
              m0 = nm; }
            { float nm = fmaxf(m1, p1), f = __expf(m1 - nm), e = __expf(p1 - nm);
              si1*=f; so1*=f; ai1x*=f; ai1y*=f; ao1x*=f; ao1y*=f;
              if (mj){ si1+=e; ai1x+=e*sx; ai1y+=e*sy; } else { so1+=e; ao1x+=e*sx; ao1y+=e*sy; }
              m1 = nm; }
            { float nm = fmaxf(m2, p2), f = __expf(m2 - nm), e = __expf(p2 - nm);
              si2*=f; so2*=f; ai2x*=f; ai2y*=f; ao2x*=f; ao2y*=f;
              if (mj){ si2+=e; ai2x+=e*cx; ai2y+=e*cy; } else { so2+=e; ao2x+=e*cx; ao2y+=e*cy; }
              m2 = nm; }
        }
    }
    size_t sstr = (size_t)npad * 64;
    size_t widx = (size_t)v * 64 + lane;
    float st, inv;
    st = si0 + so0; inv = st > 0.f ? 1.f / st : 0.f;
    Sw[0*sstr + widx] = packbf(ai0x*inv, ai0y*inv);
    Sw[1*sstr + widx] = packbf(ao0x*inv, ao0y*inv);
    float ri0 = si0*inv, ro0 = so0*inv;
    st = si1 + so1; inv = st > 0.f ? 1.f / st : 0.f;
    Sw[2*sstr + widx] = packbf(ai1x*inv, ai1y*inv);
    Sw[3*sstr + widx] = packbf(ao1x*inv, ao1y*inv);
    float ri1 = si1*inv, ro1 = so1*inv;
    st = si2 + so2; inv = st > 0.f ? 1.f / st : 0.f;
    Sw[4*sstr + widx] = packbf(ai2x*inv, ai2y*inv);
    Sw[5*sstr + widx] = packbf(ao2x*inv, ao2y*inv);
    float ri2 = si2*inv, ro2 = so2*inv;
    if (lane == 0){
        Rv[0*(size_t)npad + v] = ri0; Rv[1*(size_t)npad + v] = ro0;
        Rv[2*(size_t)npad + v] = ri1; Rv[3*(size_t)npad + v] = ro1;
        Rv[4*(size_t)npad + v] = ri2; Rv[5*(size_t)npad + v] = ro2;
    }
}

// ---------------- dense [N x 128] @ W^T GEMM (MFMA) + bias + col-stats -----
struct GArgs {
    const short* Wi[3]; const short* Wo[3];
    const float* bi[3]; const float* bo[3];
};

__global__ __launch_bounds__(256)
void k_gemm(GArgs ga, const short* Sb, const float* Rv, unsigned short* P, float* stats,
            int npad, int Nn)
{
    __shared__ float lsum[128], lsq[128];
    int t = threadIdx.x;
    if (t < 128){ lsum[t] = 0.f; lsq[t] = 0.f; }
    __syncthreads();
    int l = blockIdx.y;
    int lane = t & 63, wv = t >> 6;
    int lo = lane & 15, hi = lane >> 4;
    int r0 = blockIdx.x * 64 + wv * 16;
    size_t sstride = (size_t)npad * DN;
    const short* Sin  = Sb + (size_t)(2*l)   * sstride;
    const short* Sout = Sb + (size_t)(2*l+1) * sstride;
    const short* Wi = ga.Wi[l]; const short* Wo = ga.Wo[l];

    s16x8 ain[4], aout[4];
    #pragma unroll
    for (int kb = 0; kb < 4; ++kb){
        size_t o = (size_t)(r0 + lo) * DN + kb*32 + hi*8;
        ain[kb]  = *(const s16x8*)(Sin + o);
        aout[kb] = *(const s16x8*)(Sout + o);
    }
    float rin[4], rout[4];
    const float* RvI = Rv + (size_t)(2*l)   * npad;
    const float* RvO = Rv + (size_t)(2*l+1) * npad;
    #pragma unroll
    for (int rg = 0; rg < 4; ++rg){
        int vr = r0 + hi*4 + rg;
        rin[rg] = RvI[vr]; rout[rg] = RvO[vr];
    }
    unsigned short* Pl = P + (size_t)l * sstride;

    #pragma unroll
    for (int ct = 0; ct < 8; ++ct){
        f32x4 acc = {0.f, 0.f, 0.f, 0.f};
        #pragma unroll
        for (int kb = 0; kb < 4; ++kb){
            size_t wo = (size_t)(ct*16 + lo) * DN + kb*32 + hi*8;
            s16x8 bwi = *(const s16x8*)(Wi + wo);
            acc = __builtin_amdgcn_mfma_f32_16x16x32_bf16(ain[kb], bwi, acc, 0, 0, 0);
            s16x8 bwo = *(const s16x8*)(Wo + wo);
            acc = __builtin_amdgcn_mfma_f32_16x16x32_bf16(aout[kb], bwo, acc, 0, 0, 0);
        }
        int j = ct*16 + lo;
        float biv = ga.bi[l][j], bov = ga.bo[l][j];
        float cs = 0.f, cq = 0.f;
        #pragma unroll
        for (int rg = 0; rg < 4; ++rg){
            float pv = acc[rg] + rin[rg]*biv + rout[rg]*bov;
            Pl[(size_t)(r0 + hi*4 + rg) * DN + j] = (unsigned short)f2bf(pv);
            cs += pv; cq += pv*pv;
        }
        cs += __shfl_xor(cs, 16); cs += __shfl_xor(cs, 32);
        cq += __shfl_xor(cq, 16); cq += __shfl_xor(cq, 32);
        if (lane < 16){ atomicAdd(&lsum[j], cs); atomicAdd(&lsq[j], cq); }
    }
    __syncthreads();
    if (t < 128){
        atomicAdd(&stats[l*128 + t], lsum[t]);
        atomicAdd(&stats[384 + l*128 + t], lsq[t]);
    }
}

// ---------------- BN constants: A = g*inv_std, B = b - mu*g*inv_std --------
struct BArgs { const float* g[3]; const float* b[3]; };

__global__ void k_bn(BArgs ba, const float* stats, float* bnAB, int Nn){
    int t = threadIdx.x;
    if (t >= 384) return;
    int l = t >> 7, j = t & 127;
    float su = stats[t], sq = stats[384 + t];
    float mu = su / (float)Nn;
    float var = fmaxf(sq / (float)Nn - mu*mu, 0.f);
    float inv = rsqrtf(var + 1e-5f);
    float g = ba.g[l][j], b = ba.b[l][j];
    bnAB[t] = g * inv;
    bnAB[384 + t] = b - mu * g * inv;
}

// ---------------- final entity output: ent + sum of 3 tanh(BN(P_l)) --------
__global__ void k_final(const unsigned short* Pb, const float* bnAB, const float* ent,
                        float* outp, int Nn, int npad)
{
    int gid = blockIdx.x * blockDim.x + threadIdx.x;
    if (gid >= Nn * 32) return;
    int v = gid >> 5, q4 = (gid & 31) * 4;
    size_t pst = (size_t)npad * DN;
    size_t pb = (size_t)v * DN + q4;
    ushort4 p0 = *(const ushort4*)(Pb + pb);
    ushort4 p1 = *(const ushort4*)(Pb + pst + pb);
    ushort4 p2 = *(const ushort4*)(Pb + 2*pst + pb);
    float4 e4 = *(const float4*)(ent + (size_t)v * DN + q4);
    float pe[4] = { e4.x, e4.y, e4.z, e4.w };
    unsigned short pu[3][4] = { {p0.x, p0.y, p0.z, p0.w},
                                {p1.x, p1.y, p1.z, p1.w},
                                {p2.x, p2.y, p2.z, p2.w} };
    float o[4];
    #pragma unroll
    for (int q = 0; q < 4; ++q){
        float s = pe[q];
        #pragma unroll
        for (int l = 0; l < 3; ++l){
            int jj = l*128 + q4 + q;
            s += tanh_(bnAB[jj] * bfs(pu[l][q]) + bnAB[384 + jj]);
        }
        o[q] = s;
    }
    float4 ov = { o[0], o[1], o[2], o[3] };
    *(float4*)(outp + (size_t)v * DN + q4) = ov;
}

// ---------------- relation update: mean-then-linear (linearity) ------------
__global__ void k_rel(const float* ent, const float* relW, const float* relb,
                      const float* rel, const int* heads, const int* tails,
                      float* outr, int Sp)
{
    __shared__ float mp[128];
    int r = blockIdx.x, j = threadIdx.x;
    float acc = 0.f;
    for (int s = 0; s < Sp; ++s){
        int p = r * Sp + s;
        int hh = heads[p], tt = tails[p];
        acc += ent[(size_t)tt * DN + j] - ent[(size_t)hh * DN + j];
    }
    mp[j] = acc / (float)Sp;
    __syncthreads();
    float dot = relb[j];
    const float4* wr = (const float4*)(relW + (size_t)j * DN);
    #pragma unroll 8
    for (int kb = 0; kb < 32; ++kb){
        float4 w = wr[kb];
        dot += mp[kb*4+0]*w.x + mp[kb*4+1]*w.y + mp[kb*4+2]*w.z + mp[kb*4+3]*w.w;
    }
    outr[(size_t)r * DN + j] = rel[(size_t)r * DN + j] + tanh_(dot);
}

// ---------------------------------------------------------------------------
extern "C" void kernel_launch(void* const* d_in, const int* in_sizes, int n_in,
                              void* d_out, int out_size, void* d_ws, size_t ws_size,
                              hipStream_t stream)
{
    // setup_inputs dict order (all float arrays are f32 on device)
    const float* entf = (const float*)d_in[0];
    const float* relf = (const float*)d_in[1];
    const float* eWo = (const float*)d_in[2];  const float* ebo = (const float*)d_in[3];
    const float* eWi = (const float*)d_in[4];  const float* ebi = (const float*)d_in[5];
    const float* eg  = (const float*)d_in[6];  const float* eb  = (const float*)d_in[7];
    const float* nWo = (const float*)d_in[8];  const float* nbo = (const float*)d_in[9];
    const float* nWi = (const float*)d_in[10]; const float* nbi = (const float*)d_in[11];
    const float* ng  = (const float*)d_in[12]; const float* nb_ = (const float*)d_in[13];
    const float* cWo = (const float*)d_in[14]; const float* cbo = (const float*)d_in[15];
    const float* cWi = (const float*)d_in[16]; const float* cbi = (const float*)d_in[17];
    const float* cg  = (const float*)d_in[18]; const float* cb  = (const float*)d_in[19];
    const float* relWs  = (const float*)d_in[20];
    const float* relb32 = (const float*)d_in[21];
    const int* srcp   = (const int*)d_in[22];
    const int* dstp   = (const int*)d_in[23];
    const int* etyp   = (const int*)d_in[24];
    const int* headsp = (const int*)d_in[25];
    const int* tailsp = (const int*)d_in[26];
    const unsigned char* mask8 = (const unsigned char*)d_in[28];   // in_mask

    int Nn = in_sizes[0] / DN;
    int Rr = in_sizes[1] / DN;
    int E  = in_sizes[22];
    int Pp = in_sizes[25];
    int Sp = Pp / Rr;
    int npad = ((Nn + 255) / 256) * 256;
    int nsb = npad / 256;

    char* w = (char*)d_ws; size_t off = 0;
    auto carve = [&](size_t b) -> void* {
        void* p = w + off; off = (off + b + 255) & ~(size_t)255; return p;
    };
    int*   flag   = (int*)  carve(4);
    int*   counts = (int*)  carve((size_t)npad * 4);
    int*   rowst  = (int*)  carve((size_t)(npad + 1) * 4);
    int*   cursor = (int*)  carve((size_t)npad * 4);
    int*   eord   = (int*)  carve((size_t)E * 4);
    int*   bsums  = (int*)  carve(1024 * 4);
    unsigned short* wcv = (unsigned short*)carve((size_t)6 * 16384 * 2);
    short* Sb     = (short*)carve((size_t)6 * npad * DN * 2);
    unsigned short* Pb = (unsigned short*)carve((size_t)3 * npad * DN * 2);
    float* Rv     = (float*)carve((size_t)6 * npad * 4);
    float* stats  = (float*)carve(1024 * 4);
    float* bnAB   = (float*)carve(1024 * 4);

    hipMemsetAsync(counts, 0, (size_t)npad * 4, stream);
    hipMemsetAsync(stats, 0, 1024 * 4, stream);

    int nw = E / 4; if (nw > 4096) nw = 4096;
    k_detect<<<1, 256, 0, stream>>>((const uint32_t*)mask8, nw, flag);

    WC wc; wc.src[0] = eWi; wc.src[1] = nWi; wc.src[2] = cWi;
           wc.src[3] = eWo; wc.src[4] = nWo; wc.src[5] = cWo;
    k_wcvt<<<384, 256, 0, stream>>>(wc, wcv);

    k_hist<<<(E + 255) / 256, 256, 0, stream>>>(dstp, counts, E);
    k_scan_a<<<nsb, 256, 0, stream>>>(counts, bsums);
    k_scan_b<<<1, 256, 0, stream>>>(bsums, nsb);
    k_scan_c<<<nsb, 256, 0, stream>>>(counts, bsums, rowst, cursor, npad, E);
    k_scatter<<<(E + 255) / 256, 256, 0, stream>>>(dstp, cursor, eord, E);

    k_node<<<npad / 4, 256, 0, stream>>>((const float2*)entf, (const float2*)relf,
                                         srcp, etyp, mask8, flag,
                                         rowst, eord, (uint32_t*)Sb, Rv, Nn, npad);

    GArgs ga;
    ga.Wi[0] = (const short*)(wcv + 0*16384);
    ga.Wi[1] = (const short*)(wcv + 1*16384);
    ga.Wi[2] = (const short*)(wcv + 2*16384);
    ga.Wo[0] = (const short*)(wcv + 3*16384);
    ga.Wo[1] = (const short*)(wcv + 4*16384);
    ga.Wo[2] = (const short*)(wcv + 5*16384);
    ga.bi[0] = ebi; ga.bi[1] = nbi; ga.bi[2] = cbi;
    ga.bo[0] = ebo; ga.bo[1] = nbo; ga.bo[2] = cbo;
    k_gemm<<<dim3(npad / 64, 3), 256, 0, stream>>>(ga, Sb, Rv, Pb, stats, npad, Nn);

    BArgs ba;
    ba.g[0] = eg; ba.g[1] = ng; ba.g[2] = cg;
    ba.b[0] = eb; ba.b[1] = nb_; ba.b[2] = cb;
    k_bn<<<1, 384, 0, stream>>>(ba, stats, bnAB, Nn);

    float* outF = (float*)d_out;
    k_final<<<(Nn * 32 + 255) / 256, 256, 0, stream>>>(Pb, bnAB, entf, outF, Nn, npad);

    k_rel<<<Rr, 128, 0, stream>>>(entf, relWs, relb32, relf, headsp, tailsp,
                                  outF + (size_t)Nn * DN, Sp);
}

// Round 5
// 393.720 us; speedup vs baseline: 1.0663x; 1.0663x over previous
//
#include <hip/hip_runtime.h>
#include <stdint.h>

#define DN 128

typedef short s16x8 __attribute__((ext_vector_type(8)));
typedef float f32x4 __attribute__((ext_vector_type(4)));

__device__ __forceinline__ float bfs(unsigned short u){ return __uint_as_float(((uint32_t)u) << 16); }
__device__ __forceinline__ uint32_t f2bf(float f){
    uint32_t x = __float_as_uint(f);
    return (x + 0x7FFFu + ((x >> 16) & 1u)) >> 16;   // RTNE
}
__device__ __forceinline__ uint32_t packbf(float a, float b){ return f2bf(a) | (f2bf(b) << 16); }
__device__ __forceinline__ float tanh_(float x){
    float e = __expf(2.0f * x);
    return 1.0f - 2.0f / (e + 1.0f);
}

// ---- fused: dst histogram + mask-format detect + weight f32->bf16 ---------
struct WC { const float* src[6]; };
__global__ void k_pre(const int* dst, int* counts,
                      const uint32_t* maskw, int nwords, int* flag,
                      WC wc, unsigned short* wcv, int E){
    int gid = blockIdx.x * 256 + threadIdx.x;
    if (gid < E) atomicAdd(&counts[dst[gid]], 1);
    if (gid < nwords && maskw[gid] > 1u) atomicOr(flag, 1);
    if (gid < 6 * 16384){
        int m = gid >> 14, o = gid & 16383;
        wcv[(size_t)m * 16384 + o] = (unsigned short)f2bf(wc.src[m][o]);
    }
}

// ---- CSR scan: per-256-chunk sums -----------------------------------------
__global__ void k_scan_a(const int* counts, int* bsums){
    int t = threadIdx.x;
    int s = counts[blockIdx.x * 256 + t];
    #pragma unroll
    for (int o = 32; o; o >>= 1) s += __shfl_xor(s, o);
    __shared__ int wsum[4];
    if ((t & 63) == 0) wsum[t >> 6] = s;
    __syncthreads();
    if (t == 0) bsums[blockIdx.x] = wsum[0] + wsum[1] + wsum[2] + wsum[3];
}

// ---- CSR scan: per-block prefix over bsums + local scan -------------------
__global__ void k_scan_bc(const int* counts, const int* bsums, int nsb,
                          int* rowst, int* cursor, int npad, int E){
    __shared__ int pref;
    __shared__ int wsum[4];
    __shared__ int buf[256];
    int t = threadIdx.x, bid = blockIdx.x;
    int s = (t < bid && t < nsb) ? bsums[t] : 0;
    #pragma unroll
    for (int o = 32; o; o >>= 1) s += __shfl_xor(s, o);
    if ((t & 63) == 0) wsum[t >> 6] = s;
    __syncthreads();
    if (t == 0) pref = wsum[0] + wsum[1] + wsum[2] + wsum[3];
    int i = bid * 256 + t;
    int c = counts[i];
    buf[t] = c;
    __syncthreads();
    for (int o = 1; o < 256; o <<= 1){
        int add = (t >= o) ? buf[t - o] : 0;
        __syncthreads();
        buf[t] += add;
        __syncthreads();
    }
    int rsv = buf[t] - c + pref;
    rowst[i] = rsv; cursor[i] = rsv;
    if (i == npad - 1) rowst[npad] = E;
}

// ---- scatter edges into CSR order as packed records -----------------------
// epack = src[31:16] | etype[15:1] | mask[0]
__global__ void k_scatter(const int* dst, const int* src, const int* etype,
                          const unsigned char* mask8, const int* flagp,
                          int* cursor, uint32_t* epack, int E){
    int e = blockIdx.x * blockDim.x + threadIdx.x;
    if (e >= E) return;
    int bmode = *flagp;
    int mk = bmode ? (int)mask8[e] : ((const int*)mask8)[e];
    int pos = atomicAdd(&cursor[dst[e]], 1);
    epack[pos] = ((uint32_t)src[e] << 16) | ((uint32_t)etype[e] << 1) | (uint32_t)(mk != 0);
}

// ---- per-node fused 3-layer online softmax, 2 edges per wave --------------
// lanes 0-31 = even edges, lanes 32-63 = odd edges (same dst node); each lane
// holds float4 = elements sl*4..sl*4+3 of the D=128 row. Unconditional
// per-pair rescale (round-2 recurrence); padded lanes use p=-1e38 so the
// running max is never touched by garbage rows. Half-streams merged at end.
__global__ __launch_bounds__(256)
void k_node(const float4* ent4, const float4* rel4,
            const uint32_t* epack, const int* rowst,
            uint32_t* Sw, float* Rv, int Nn, int npad)
{
    int t = threadIdx.x, lane = t & 63, wv = t >> 6;
    int v = blockIdx.x * 4 + wv;
    if (v >= npad) return;
    int sl = lane & 31, half = lane >> 5;

    float4 d4 = {0.f, 0.f, 0.f, 0.f};
    int deg = 0, rs = 0;
    if (v < Nn){
        rs = rowst[v]; deg = rowst[v + 1] - rs;
        d4 = ent4[(size_t)v * 32 + sl];
    }
    float m0 = -1e30f, m1 = -1e30f, m2 = -1e30f;
    float si0 = 0, si1 = 0, si2 = 0, so0 = 0, so1 = 0, so2 = 0;
    float4 aI0 = {0,0,0,0}, aO0 = {0,0,0,0};
    float4 aI1 = {0,0,0,0}, aO1 = {0,0,0,0};
    float4 aI2 = {0,0,0,0}, aO2 = {0,0,0,0};

    for (int base = 0; base < deg; base += 64){
        int nb = min(64, deg - base);
        uint32_t pk = 0;
        if (lane < nb) pk = epack[rs + base + lane];
        int npair = (nb + 1) >> 1;
        for (int j = 0; j < npair; ++j){
            int ei = 2 * j + half;
            uint32_t w = (uint32_t)__shfl((int)pk, ei);
            int sj = (int)(w >> 16);
            int tj = (int)((w >> 1) & 0x7FFF);
            float mk = (float)(w & 1u);
            bool pad = (ei >= nb);
            float4 s4 = ent4[(size_t)sj * 32 + sl];
            float4 r4 = rel4[(size_t)tj * 32 + sl];
            float4 c4 = { s4.x*r4.x, s4.y*r4.y, s4.z*r4.z, s4.w*r4.w };
            float p0 = r4.x*d4.x + r4.y*d4.y + r4.z*d4.z + r4.w*d4.w;
            float p1 = s4.x*d4.x + s4.y*d4.y + s4.z*d4.z + s4.w*d4.w;
            float p2 = c4.x*d4.x + c4.y*d4.y + c4.z*d4.z + c4.w*d4.w;
            #pragma unroll
            for (int o = 1; o < 32; o <<= 1){
                p0 += __shfl_xor(p0, o);
                p1 += __shfl_xor(p1, o);
                p2 += __shfl_xor(p2, o);
            }
            if (pad){ p0 = -1e38f; p1 = -1e38f; p2 = -1e38f; }
            // layer 0 (message = rel row)
            {
                float nm = fmaxf(m0, p0);
                float f = __expf(m0 - nm);
                si0 *= f; so0 *= f;
                aI0.x*=f; aI0.y*=f; aI0.z*=f; aI0.w*=f;
                aO0.x*=f; aO0.y*=f; aO0.z*=f; aO0.w*=f;
                m0 = nm;
                float e = __expf(p0 - m0);
                float ein = e * mk, eout = e - ein;
                si0 += ein; so0 += eout;
                aI0.x += ein*r4.x; aI0.y += ein*r4.y; aI0.z += ein*r4.z; aI0.w += ein*r4.w;
                aO0.x += eout*r4.x; aO0.y += eout*r4.y; aO0.z += eout*r4.z; aO0.w += eout*r4.w;
            }
            // layer 1 (message = src row)
            {
                float nm = fmaxf(m1, p1);
                float f = __expf(m1 - nm);
                si1 *= f; so1 *= f;
                aI1.x*=f; aI1.y*=f; aI1.z*=f; aI1.w*=f;
                aO1.x*=f; aO1.y*=f; aO1.z*=f; aO1.w*=f;
                m1 = nm;
                float e = __expf(p1 - m1);
                float ein = e * mk, eout = e - ein;
                si1 += ein; so1 += eout;
                aI1.x += ein*s4.x; aI1.y += ein*s4.y; aI1.z += ein*s4.z; aI1.w += ein*s4.w;
                aO1.x += eout*s4.x; aO1.y += eout*s4.y; aO1.z += eout*s4.z; aO1.w += eout*s4.w;
            }
            // layer 2 (message = src*rel row)
            {
                float nm = fmaxf(m2, p2);
                float f = __expf(m2 - nm);
                si2 *= f; so2 *= f;
                aI2.x*=f; aI2.y*=f; aI2.z*=f; aI2.w*=f;
                aO2.x*=f; aO2.y*=f; aO2.z*=f; aO2.w*=f;
                m2 = nm;
                float e = __expf(p2 - m2);
                float ein = e * mk, eout = e - ein;
                si2 += ein; so2 += eout;
                aI2.x += ein*c4.x; aI2.y += ein*c4.y; aI2.z += ein*c4.z; aI2.w += ein*c4.w;
                aO2.x += eout*c4.x; aO2.y += eout*c4.y; aO2.z += eout*c4.z; aO2.w += eout*c4.w;
            }
        }
    }

    // merge the two half-streams (flash-style rescale to common max)
    {
        float mo, nm, f;
#define MRG(m, si, so, aI, aO)                                            \
        mo = __shfl_xor(m, 32);                                           \
        nm = fmaxf(m, mo);                                                \
        f = __expf(m - nm);                                               \
        si *= f; so *= f;                                                 \
        aI.x*=f; aI.y*=f; aI.z*=f; aI.w*=f;                               \
        aO.x*=f; aO.y*=f; aO.z*=f; aO.w*=f;                               \
        si += __shfl_xor(si, 32);                                         \
        so += __shfl_xor(so, 32);                                         \
        aI.x += __shfl_xor(aI.x, 32); aI.y += __shfl_xor(aI.y, 32);       \
        aI.z += __shfl_xor(aI.z, 32); aI.w += __shfl_xor(aI.w, 32);       \
        aO.x += __shfl_xor(aO.x, 32); aO.y += __shfl_xor(aO.y, 32);       \
        aO.z += __shfl_xor(aO.z, 32); aO.w += __shfl_xor(aO.w, 32);
        MRG(m0, si0, so0, aI0, aO0)
        MRG(m1, si1, so1, aI1, aO1)
        MRG(m2, si2, so2, aI2, aO2)
#undef MRG
    }

    if (half == 0){
        uint2* S2 = (uint2*)Sw;
        size_t s2 = (size_t)npad * 32;
        size_t wi = (size_t)v * 32 + sl;
        float st, inv;
        st = si0 + so0; inv = st > 0.f ? 1.f / st : 0.f;
        S2[0*s2 + wi] = make_uint2(packbf(aI0.x*inv, aI0.y*inv), packbf(aI0.z*inv, aI0.w*inv));
        S2[1*s2 + wi] = make_uint2(packbf(aO0.x*inv, aO0.y*inv), packbf(aO0.z*inv, aO0.w*inv));
        float ri0 = si0*inv, ro0 = so0*inv;
        st = si1 + so1; inv = st > 0.f ? 1.f / st : 0.f;
        S2[2*s2 + wi] = make_uint2(packbf(aI1.x*inv, aI1.y*inv), packbf(aI1.z*inv, aI1.w*inv));
        S2[3*s2 + wi] = make_uint2(packbf(aO1.x*inv, aO1.y*inv), packbf(aO1.z*inv, aO1.w*inv));
        float ri1 = si1*inv, ro1 = so1*inv;
        st = si2 + so2; inv = st > 0.f ? 1.f / st : 0.f;
        S2[4*s2 + wi] = make_uint2(packbf(aI2.x*inv, aI2.y*inv), packbf(aI2.z*inv, aI2.w*inv));
        S2[5*s2 + wi] = make_uint2(packbf(aO2.x*inv, aO2.y*inv), packbf(aO2.z*inv, aO2.w*inv));
        float ri2 = si2*inv, ro2 = so2*inv;
        if (sl == 0){
            Rv[0*(size_t)npad + v] = ri0; Rv[1*(size_t)npad + v] = ro0;
            Rv[2*(size_t)npad + v] = ri1; Rv[3*(size_t)npad + v] = ro1;
            Rv[4*(size_t)npad + v] = ri2; Rv[5*(size_t)npad + v] = ro2;
        }
    }
}

// ---- dense [N x 128] @ W^T GEMM (MFMA) + bias + col stats -----------------
struct GArgs {
    const short* Wi[3]; const short* Wo[3];
    const float* bi[3]; const float* bo[3];
};

__global__ __launch_bounds__(256)
void k_gemm(GArgs ga, const short* Sb, const float* Rv, unsigned short* P, float* stats,
            int npad, int Nn)
{
    __shared__ float lsum[128], lsq[128];
    int t = threadIdx.x;
    if (t < 128){ lsum[t] = 0.f; lsq[t] = 0.f; }
    __syncthreads();
    int l = blockIdx.y;
    int lane = t & 63, wv = t >> 6;
    int lo = lane & 15, hi = lane >> 4;
    int r0 = blockIdx.x * 64 + wv * 16;
    size_t sstride = (size_t)npad * DN;
    const short* Sin  = Sb + (size_t)(2*l)   * sstride;
    const short* Sout = Sb + (size_t)(2*l+1) * sstride;
    const short* Wi = ga.Wi[l]; const short* Wo = ga.Wo[l];

    s16x8 ain[4], aout[4];
    #pragma unroll
    for (int kb = 0; kb < 4; ++kb){
        size_t o = (size_t)(r0 + lo) * DN + kb*32 + hi*8;
        ain[kb]  = *(const s16x8*)(Sin + o);
        aout[kb] = *(const s16x8*)(Sout + o);
    }
    float rin[4], rout[4];
    const float* RvI = Rv + (size_t)(2*l)   * npad;
    const float* RvO = Rv + (size_t)(2*l+1) * npad;
    #pragma unroll
    for (int rg = 0; rg < 4; ++rg){
        int vr = r0 + hi*4 + rg;
        rin[rg] = RvI[vr]; rout[rg] = RvO[vr];
    }
    unsigned short* Pl = P + (size_t)l * sstride;

    #pragma unroll
    for (int ct = 0; ct < 8; ++ct){
        f32x4 acc = {0.f, 0.f, 0.f, 0.f};
        #pragma unroll
        for (int kb = 0; kb < 4; ++kb){
            size_t wo = (size_t)(ct*16 + lo) * DN + kb*32 + hi*8;
            s16x8 bwi = *(const s16x8*)(Wi + wo);
            acc = __builtin_amdgcn_mfma_f32_16x16x32_bf16(ain[kb], bwi, acc, 0, 0, 0);
            s16x8 bwo = *(const s16x8*)(Wo + wo);
            acc = __builtin_amdgcn_mfma_f32_16x16x32_bf16(aout[kb], bwo, acc, 0, 0, 0);
        }
        int j = ct*16 + lo;
        float biv = ga.bi[l][j], bov = ga.bo[l][j];
        float cs = 0.f, cq = 0.f;
        #pragma unroll
        for (int rg = 0; rg < 4; ++rg){
            float pv = acc[rg] + rin[rg]*biv + rout[rg]*bov;
            Pl[(size_t)(r0 + hi*4 + rg) * DN + j] = (unsigned short)f2bf(pv);
            cs += pv; cq += pv*pv;
        }
        cs += __shfl_xor(cs, 16); cs += __shfl_xor(cs, 32);
        cq += __shfl_xor(cq, 16); cq += __shfl_xor(cq, 32);
        if (lane < 16){ atomicAdd(&lsum[j], cs); atomicAdd(&lsq[j], cq); }
    }
    __syncthreads();
    if (t < 128){
        atomicAdd(&stats[l*128 + t], lsum[t]);
        atomicAdd(&stats[384 + l*128 + t], lsq[t]);
    }
}

// ---- fused final: BN-const recompute + ent output | relation update -------
struct FArgs { const float* g[3]; const float* b[3]; };

__global__ __launch_bounds__(256)
void k_fin(const unsigned short* Pb, const float* stats, FArgs fa,
           const float* ent, const float* relW, const float* relb,
           const float* rel, const int* heads, const int* tails,
           float* outp, int Nn, int npad, int FB, int Sp)
{
    int t = threadIdx.x, bid = blockIdx.x;
    if (bid < FB){
        __shared__ float sAB[768];
        for (int i = t; i < 384; i += 256){
            int l = i >> 7;
            float su = stats[i], sq = stats[384 + i];
            float mu = su / (float)Nn;
            float var = fmaxf(sq / (float)Nn - mu*mu, 0.f);
            float inv = rsqrtf(var + 1e-5f);
            float g = fa.g[l][i & 127], b = fa.b[l][i & 127];
            sAB[i] = g * inv;
            sAB[384 + i] = b - mu * g * inv;
        }
        __syncthreads();
        int gid = bid * 256 + t;
        if (gid >= Nn * 32) return;
        int v = gid >> 5, q4 = (gid & 31) * 4;
        size_t pst = (size_t)npad * DN;
        size_t pb = (size_t)v * DN + q4;
        ushort4 p0 = *(const ushort4*)(Pb + pb);
        ushort4 p1 = *(const ushort4*)(Pb + pst + pb);
        ushort4 p2 = *(const ushort4*)(Pb + 2*pst + pb);
        float4 e4 = *(const float4*)(ent + (size_t)v * DN + q4);
        float pe[4] = { e4.x, e4.y, e4.z, e4.w };
        unsigned short pu[3][4] = { {p0.x, p0.y, p0.z, p0.w},
                                    {p1.x, p1.y, p1.z, p1.w},
                                    {p2.x, p2.y, p2.z, p2.w} };
        float o[4];
        #pragma unroll
        for (int q = 0; q < 4; ++q){
            float s = pe[q];
            #pragma unroll
            for (int l = 0; l < 3; ++l){
                int jj = l*128 + q4 + q;
                s += tanh_(sAB[jj] * bfs(pu[l][q]) + sAB[384 + jj]);
            }
            o[q] = s;
        }
        float4 ov = { o[0], o[1], o[2], o[3] };
        *(float4*)(outp + (size_t)v * DN + q4) = ov;
    } else {
        __shared__ float mp[256];
        int rr = (bid - FB) * 2 + (t >> 7);
        int j = t & 127;
        float acc = 0.f;
        for (int s = 0; s < Sp; ++s){
            int p = rr * Sp + s;
            acc += ent[(size_t)tails[p] * DN + j] - ent[(size_t)heads[p] * DN + j];
        }
        mp[t] = acc / (float)Sp;
        __syncthreads();
        float dot = relb[j];
        const float4* wr = (const float4*)(relW + (size_t)j * DN);
        const float* mpr = mp + (t >> 7) * 128;
        #pragma unroll 8
        for (int kb = 0; kb < 32; ++kb){
            float4 w = wr[kb];
            dot += mpr[kb*4+0]*w.x + mpr[kb*4+1]*w.y + mpr[kb*4+2]*w.z + mpr[kb*4+3]*w.w;
        }
        outp[(size_t)Nn * DN + (size_t)rr * DN + j] = rel[(size_t)rr * DN + j] + tanh_(dot);
    }
}

// ---------------------------------------------------------------------------
extern "C" void kernel_launch(void* const* d_in, const int* in_sizes, int n_in,
                              void* d_out, int out_size, void* d_ws, size_t ws_size,
                              hipStream_t stream)
{
    const float* entf = (const float*)d_in[0];
    const float* relf = (const float*)d_in[1];
    const float* eWo = (const float*)d_in[2];  const float* ebo = (const float*)d_in[3];
    const float* eWi = (const float*)d_in[4];  const float* ebi = (const float*)d_in[5];
    const float* eg  = (const float*)d_in[6];  const float* eb  = (const float*)d_in[7];
    const float* nWo = (const float*)d_in[8];  const float* nbo = (const float*)d_in[9];
    const float* nWi = (const float*)d_in[10]; const float* nbi = (const float*)d_in[11];
    const float* ng  = (const float*)d_in[12]; const float* nb_ = (const float*)d_in[13];
    const float* cWo = (const float*)d_in[14]; const float* cbo = (const float*)d_in[15];
    const float* cWi = (const float*)d_in[16]; const float* cbi = (const float*)d_in[17];
    const float* cg  = (const float*)d_in[18]; const float* cb  = (const float*)d_in[19];
    const float* relWs  = (const float*)d_in[20];
    const float* relb32 = (const float*)d_in[21];
    const int* srcp   = (const int*)d_in[22];
    const int* dstp   = (const int*)d_in[23];
    const int* etyp   = (const int*)d_in[24];
    const int* headsp = (const int*)d_in[25];
    const int* tailsp = (const int*)d_in[26];
    const unsigned char* mask8 = (const unsigned char*)d_in[28];   // in_mask

    int Nn = in_sizes[0] / DN;
    int Rr = in_sizes[1] / DN;
    int E  = in_sizes[22];
    int Pp = in_sizes[25];
    int Sp = Pp / Rr;
    int npad = ((Nn + 255) / 256) * 256;
    int nsb = npad / 256;

    char* w = (char*)d_ws; size_t off = 0;
    auto carve = [&](size_t b) -> void* {
        void* p = w + off; off = (off + b + 255) & ~(size_t)255; return p;
    };
    // zero-region first (flag | counts | stats), one memset covers all three
    int*   flag   = (int*)  carve(4);
    int*   counts = (int*)  carve((size_t)npad * 4);
    float* stats  = (float*)carve(1024 * 4);
    size_t zlen = off;
    int*   rowst  = (int*)  carve((size_t)(npad + 1) * 4);
    int*   cursor = (int*)  carve((size_t)npad * 4);
    uint32_t* epack = (uint32_t*)carve((size_t)E * 4);
    int*   bsums  = (int*)  carve(1024 * 4);
    unsigned short* wcv = (unsigned short*)carve((size_t)6 * 16384 * 2);
    short* Sb     = (short*)carve((size_t)6 * npad * DN * 2);
    unsigned short* Pb = (unsigned short*)carve((size_t)3 * npad * DN * 2);
    float* Rv     = (float*)carve((size_t)6 * npad * 4);

    hipMemsetAsync(d_ws, 0, zlen, stream);

    WC wc; wc.src[0] = eWi; wc.src[1] = nWi; wc.src[2] = cWi;
           wc.src[3] = eWo; wc.src[4] = nWo; wc.src[5] = cWo;
    int nwords = 4096;
    k_pre<<<(E + 255) / 256, 256, 0, stream>>>(dstp, counts, (const uint32_t*)mask8,
                                               nwords, flag, wc, wcv, E);
    k_scan_a<<<nsb, 256, 0, stream>>>(counts, bsums);
    k_scan_bc<<<nsb, 256, 0, stream>>>(counts, bsums, nsb, rowst, cursor, npad, E);
    k_scatter<<<(E + 255) / 256, 256, 0, stream>>>(dstp, srcp, etyp, mask8, flag,
                                                   cursor, epack, E);

    k_node<<<npad / 4, 256, 0, stream>>>((const float4*)entf, (const float4*)relf,
                                         epack, rowst, (uint32_t*)Sb, Rv, Nn, npad);

    GArgs ga;
    ga.Wi[0] = (const short*)(wcv + 0*16384);
    ga.Wi[1] = (const short*)(wcv + 1*16384);
    ga.Wi[2] = (const short*)(wcv + 2*16384);
    ga.Wo[0] = (const short*)(wcv + 3*16384);
    ga.Wo[1] = (const short*)(wcv + 4*16384);
    ga.Wo[2] = (const short*)(wcv + 5*16384);
    ga.bi[0] = ebi; ga.bi[1] = nbi; ga.bi[2] = cbi;
    ga.bo[0] = ebo; ga.bo[1] = nbo; ga.bo[2] = cbo;
    k_gemm<<<dim3(npad / 64, 3), 256, 0, stream>>>(ga, Sb, Rv, Pb, stats, npad, Nn);

    FArgs fa;
    fa.g[0] = eg; fa.g[1] = ng; fa.g[2] = cg;
    fa.b[0] = eb; fa.b[1] = nb_; fa.b[2] = cb;
    int FB = (Nn * 32 + 255) / 256;
    int grid = FB + Rr / 2;
    k_fin<<<grid, 256, 0, stream>>>(Pb, stats, fa, entf, relWs, relb32, relf,
                                    headsp, tailsp, (float*)d_out, Nn, npad, FB, Sp);
}

// Round 6
// 391.949 us; speedup vs baseline: 1.0711x; 1.0045x over previous
//
#include <hip/hip_runtime.h>
#include <stdint.h>

#define DN 128
#define NSTAT 64

typedef short s16x8 __attribute__((ext_vector_type(8)));
typedef float f32x4 __attribute__((ext_vector_type(4)));

__device__ __forceinline__ float bfs(unsigned short u){ return __uint_as_float(((uint32_t)u) << 16); }
__device__ __forceinline__ uint32_t f2bf(float f){
    uint32_t x = __float_as_uint(f);
    return (x + 0x7FFFu + ((x >> 16) & 1u)) >> 16;   // RTNE
}
__device__ __forceinline__ uint32_t packbf(float a, float b){ return f2bf(a) | (f2bf(b) << 16); }
__device__ __forceinline__ float tanh_(float x){
    float e = __expf(2.0f * x);
    return 1.0f - 2.0f / (e + 1.0f);
}

// ---- fused: dst histogram + mask-format detect + weight f32->bf16 ---------
struct WC { const float* src[6]; };
__global__ void k_pre(const int* dst, int* counts,
                      const uint32_t* maskw, int nwords, int* flag,
                      WC wc, unsigned short* wcv, int E){
    int gid = blockIdx.x * 256 + threadIdx.x;
    if (gid < E) atomicAdd(&counts[dst[gid]], 1);
    if (gid < nwords && maskw[gid] > 1u) atomicOr(flag, 1);
    if (gid < 6 * 16384){
        int m = gid >> 14, o = gid & 16383;
        wcv[(size_t)m * 16384 + o] = (unsigned short)f2bf(wc.src[m][o]);
    }
}

// ---- CSR scan: per-256-chunk sums -----------------------------------------
__global__ void k_scan_a(const int* counts, int* bsums){
    int t = threadIdx.x;
    int s = counts[blockIdx.x * 256 + t];
    #pragma unroll
    for (int o = 32; o; o >>= 1) s += __shfl_xor(s, o);
    __shared__ int wsum[4];
    if ((t & 63) == 0) wsum[t >> 6] = s;
    __syncthreads();
    if (t == 0) bsums[blockIdx.x] = wsum[0] + wsum[1] + wsum[2] + wsum[3];
}

// ---- CSR scan: per-block prefix over bsums + local scan -------------------
__global__ void k_scan_bc(const int* counts, const int* bsums, int nsb,
                          int* rowst, int* cursor, int npad, int E){
    __shared__ int pref;
    __shared__ int wsum[4];
    __shared__ int buf[256];
    int t = threadIdx.x, bid = blockIdx.x;
    int s = (t < bid && t < nsb) ? bsums[t] : 0;
    #pragma unroll
    for (int o = 32; o; o >>= 1) s += __shfl_xor(s, o);
    if ((t & 63) == 0) wsum[t >> 6] = s;
    __syncthreads();
    if (t == 0) pref = wsum[0] + wsum[1] + wsum[2] + wsum[3];
    int i = bid * 256 + t;
    int c = counts[i];
    buf[t] = c;
    __syncthreads();
    for (int o = 1; o < 256; o <<= 1){
        int add = (t >= o) ? buf[t - o] : 0;
        __syncthreads();
        buf[t] += add;
        __syncthreads();
    }
    int rsv = buf[t] - c + pref;
    rowst[i] = rsv; cursor[i] = rsv;
    if (i == npad - 1) rowst[npad] = E;
}

// ---- scatter edges into CSR order as packed records -----------------------
// epack = src[31:16] | etype[15:1] | mask[0]
__global__ void k_scatter(const int* dst, const int* src, const int* etype,
                          const unsigned char* mask8, const int* flagp,
                          int* cursor, uint32_t* epack, int E){
    int e = blockIdx.x * blockDim.x + threadIdx.x;
    if (e >= E) return;
    int bmode = *flagp;
    int mk = bmode ? (int)mask8[e] : ((const int*)mask8)[e];
    int pos = atomicAdd(&cursor[dst[e]], 1);
    epack[pos] = ((uint32_t)src[e] << 16) | ((uint32_t)etype[e] << 1) | (uint32_t)(mk != 0);
}

// ---- per-node fused 3-layer online softmax, 2 edges per wave --------------
__global__ __launch_bounds__(256)
void k_node(const float4* ent4, const float4* rel4,
            const uint32_t* epack, const int* rowst,
            uint32_t* Sw, float* Rv, int Nn, int npad)
{
    int t = threadIdx.x, lane = t & 63, wv = t >> 6;
    int v = blockIdx.x * 4 + wv;
    if (v >= npad) return;
    int sl = lane & 31, half = lane >> 5;

    float4 d4 = {0.f, 0.f, 0.f, 0.f};
    int deg = 0, rs = 0;
    if (v < Nn){
        rs = rowst[v]; deg = rowst[v + 1] - rs;
        d4 = ent4[(size_t)v * 32 + sl];
    }
    float m0 = -1e30f, m1 = -1e30f, m2 = -1e30f;
    float si0 = 0, si1 = 0, si2 = 0, so0 = 0, so1 = 0, so2 = 0;
    float4 aI0 = {0,0,0,0}, aO0 = {0,0,0,0};
    float4 aI1 = {0,0,0,0}, aO1 = {0,0,0,0};
    float4 aI2 = {0,0,0,0}, aO2 = {0,0,0,0};

    for (int base = 0; base < deg; base += 64){
        int nb = min(64, deg - base);
        uint32_t pk = 0;
        if (lane < nb) pk = epack[rs + base + lane];
        int npair = (nb + 1) >> 1;
        for (int j = 0; j < npair; ++j){
            int ei = 2 * j + half;
            uint32_t w = (uint32_t)__shfl((int)pk, ei);
            int sj = (int)(w >> 16);
            int tj = (int)((w >> 1) & 0x7FFF);
            float mk = (float)(w & 1u);
            bool pad = (ei >= nb);
            float4 s4 = ent4[(size_t)sj * 32 + sl];
            float4 r4 = rel4[(size_t)tj * 32 + sl];
            float4 c4 = { s4.x*r4.x, s4.y*r4.y, s4.z*r4.z, s4.w*r4.w };
            float p0 = r4.x*d4.x + r4.y*d4.y + r4.z*d4.z + r4.w*d4.w;
            float p1 = s4.x*d4.x + s4.y*d4.y + s4.z*d4.z + s4.w*d4.w;
            float p2 = c4.x*d4.x + c4.y*d4.y + c4.z*d4.z + c4.w*d4.w;
            #pragma unroll
            for (int o = 1; o < 32; o <<= 1){
                p0 += __shfl_xor(p0, o);
                p1 += __shfl_xor(p1, o);
                p2 += __shfl_xor(p2, o);
            }
            if (pad){ p0 = -1e38f; p1 = -1e38f; p2 = -1e38f; }
            // layer 0 (message = rel row)
            {
                float nm = fmaxf(m0, p0);
                float f = __expf(m0 - nm);
                si0 *= f; so0 *= f;
                aI0.x*=f; aI0.y*=f; aI0.z*=f; aI0.w*=f;
                aO0.x*=f; aO0.y*=f; aO0.z*=f; aO0.w*=f;
                m0 = nm;
                float e = __expf(p0 - m0);
                float ein = e * mk, eout = e - ein;
                si0 += ein; so0 += eout;
                aI0.x += ein*r4.x; aI0.y += ein*r4.y; aI0.z += ein*r4.z; aI0.w += ein*r4.w;
                aO0.x += eout*r4.x; aO0.y += eout*r4.y; aO0.z += eout*r4.z; aO0.w += eout*r4.w;
            }
            // layer 1 (message = src row)
            {
                float nm = fmaxf(m1, p1);
                float f = __expf(m1 - nm);
                si1 *= f; so1 *= f;
                aI1.x*=f; aI1.y*=f; aI1.z*=f; aI1.w*=f;
                aO1.x*=f; aO1.y*=f; aO1.z*=f; aO1.w*=f;
                m1 = nm;
                float e = __expf(p1 - m1);
                float ein = e * mk, eout = e - ein;
                si1 += ein; so1 += eout;
                aI1.x += ein*s4.x; aI1.y += ein*s4.y; aI1.z += ein*s4.z; aI1.w += ein*s4.w;
                aO1.x += eout*s4.x; aO1.y += eout*s4.y; aO1.z += eout*s4.z; aO1.w += eout*s4.w;
            }
            // layer 2 (message = src*rel row)
            {
                float nm = fmaxf(m2, p2);
                float f = __expf(m2 - nm);
                si2 *= f; so2 *= f;
                aI2.x*=f; aI2.y*=f; aI2.z*=f; aI2.w*=f;
                aO2.x*=f; aO2.y*=f; aO2.z*=f; aO2.w*=f;
                m2 = nm;
                float e = __expf(p2 - m2);
                float ein = e * mk, eout = e - ein;
                si2 += ein; so2 += eout;
                aI2.x += ein*c4.x; aI2.y += ein*c4.y; aI2.z += ein*c4.z; aI2.w += ein*c4.w;
                aO2.x += eout*c4.x; aO2.y += eout*c4.y; aO2.z += eout*c4.z; aO2.w += eout*c4.w;
            }
        }
    }

    // merge the two half-streams (flash-style rescale to common max)
    {
        float mo, nm, f;
#define MRG(m, si, so, aI, aO)                                            \
        mo = __shfl_xor(m, 32);                                           \
        nm = fmaxf(m, mo);                                                \
        f = __expf(m - nm);                                               \
        si *= f; so *= f;                                                 \
        aI.x*=f; aI.y*=f; aI.z*=f; aI.w*=f;                               \
        aO.x*=f; aO.y*=f; aO.z*=f; aO.w*=f;                               \
        si += __shfl_xor(si, 32);                                         \
        so += __shfl_xor(so, 32);                                         \
        aI.x += __shfl_xor(aI.x, 32); aI.y += __shfl_xor(aI.y, 32);       \
        aI.z += __shfl_xor(aI.z, 32); aI.w += __shfl_xor(aI.w, 32);       \
        aO.x += __shfl_xor(aO.x, 32); aO.y += __shfl_xor(aO.y, 32);       \
        aO.z += __shfl_xor(aO.z, 32); aO.w += __shfl_xor(aO.w, 32);
        MRG(m0, si0, so0, aI0, aO0)
        MRG(m1, si1, so1, aI1, aO1)
        MRG(m2, si2, so2, aI2, aO2)
#undef MRG
    }

    if (half == 0){
        uint2* S2 = (uint2*)Sw;
        size_t s2 = (size_t)npad * 32;
        size_t wi = (size_t)v * 32 + sl;
        float st, inv;
        st = si0 + so0; inv = st > 0.f ? 1.f / st : 0.f;
        S2[0*s2 + wi] = make_uint2(packbf(aI0.x*inv, aI0.y*inv), packbf(aI0.z*inv, aI0.w*inv));
        S2[1*s2 + wi] = make_uint2(packbf(aO0.x*inv, aO0.y*inv), packbf(aO0.z*inv, aO0.w*inv));
        float ri0 = si0*inv, ro0 = so0*inv;
        st = si1 + so1; inv = st > 0.f ? 1.f / st : 0.f;
        S2[2*s2 + wi] = make_uint2(packbf(aI1.x*inv, aI1.y*inv), packbf(aI1.z*inv, aI1.w*inv));
        S2[3*s2 + wi] = make_uint2(packbf(aO1.x*inv, aO1.y*inv), packbf(aO1.z*inv, aO1.w*inv));
        float ri1 = si1*inv, ro1 = so1*inv;
        st = si2 + so2; inv = st > 0.f ? 1.f / st : 0.f;
        S2[4*s2 + wi] = make_uint2(packbf(aI2.x*inv, aI2.y*inv), packbf(aI2.z*inv, aI2.w*inv));
        S2[5*s2 + wi] = make_uint2(packbf(aO2.x*inv, aO2.y*inv), packbf(aO2.z*inv, aO2.w*inv));
        float ri2 = si2*inv, ro2 = so2*inv;
        if (sl == 0){
            Rv[0*(size_t)npad + v] = ri0; Rv[1*(size_t)npad + v] = ro0;
            Rv[2*(size_t)npad + v] = ri1; Rv[3*(size_t)npad + v] = ro1;
            Rv[4*(size_t)npad + v] = ri2; Rv[5*(size_t)npad + v] = ro2;
        }
    }
}

// ---- dense [N x 128] @ W^T GEMM (MFMA) + bias + col stats (64 partials) ---
struct GArgs {
    const short* Wi[3]; const short* Wo[3];
    const float* bi[3]; const float* bo[3];
};

__global__ __launch_bounds__(256)
void k_gemm(GArgs ga, const short* Sb, const float* Rv, unsigned short* P,
            float* statsP, int npad, int Nn)
{
    __shared__ float lsum[128], lsq[128];
    int t = threadIdx.x;
    if (t < 128){ lsum[t] = 0.f; lsq[t] = 0.f; }
    __syncthreads();
    int l = blockIdx.y;
    int lane = t & 63, wv = t >> 6;
    int lo = lane & 15, hi = lane >> 4;
    int r0 = blockIdx.x * 64 + wv * 16;
    size_t sstride = (size_t)npad * DN;
    const short* Sin  = Sb + (size_t)(2*l)   * sstride;
    const short* Sout = Sb + (size_t)(2*l+1) * sstride;
    const short* Wi = ga.Wi[l]; const short* Wo = ga.Wo[l];

    s16x8 ain[4], aout[4];
    #pragma unroll
    for (int kb = 0; kb < 4; ++kb){
        size_t o = (size_t)(r0 + lo) * DN + kb*32 + hi*8;
        ain[kb]  = *(const s16x8*)(Sin + o);
        aout[kb] = *(const s16x8*)(Sout + o);
    }
    float rin[4], rout[4];
    const float* RvI = Rv + (size_t)(2*l)   * npad;
    const float* RvO = Rv + (size_t)(2*l+1) * npad;
    #pragma unroll
    for (int rg = 0; rg < 4; ++rg){
        int vr = r0 + hi*4 + rg;
        rin[rg] = RvI[vr]; rout[rg] = RvO[vr];
    }
    unsigned short* Pl = P + (size_t)l * sstride;

    #pragma unroll
    for (int ct = 0; ct < 8; ++ct){
        f32x4 acc = {0.f, 0.f, 0.f, 0.f};
        #pragma unroll
        for (int kb = 0; kb < 4; ++kb){
            size_t wo = (size_t)(ct*16 + lo) * DN + kb*32 + hi*8;
            s16x8 bwi = *(const s16x8*)(Wi + wo);
            acc = __builtin_amdgcn_mfma_f32_16x16x32_bf16(ain[kb], bwi, acc, 0, 0, 0);
            s16x8 bwo = *(const s16x8*)(Wo + wo);
            acc = __builtin_amdgcn_mfma_f32_16x16x32_bf16(aout[kb], bwo, acc, 0, 0, 0);
        }
        int j = ct*16 + lo;
        float biv = ga.bi[l][j], bov = ga.bo[l][j];
        float cs = 0.f, cq = 0.f;
        #pragma unroll
        for (int rg = 0; rg < 4; ++rg){
            float pv = acc[rg] + rin[rg]*biv + rout[rg]*bov;
            Pl[(size_t)(r0 + hi*4 + rg) * DN + j] = (unsigned short)f2bf(pv);
            cs += pv; cq += pv*pv;
        }
        cs += __shfl_xor(cs, 16); cs += __shfl_xor(cs, 32);
        cq += __shfl_xor(cq, 16); cq += __shfl_xor(cq, 32);
        if (lane < 16){ atomicAdd(&lsum[j], cs); atomicAdd(&lsq[j], cq); }
    }
    __syncthreads();
    // spread global atomics across NSTAT partial buffers (cross-XCD contention fix)
    float* stats = statsP + (size_t)((blockIdx.x ^ (blockIdx.y << 4)) & (NSTAT-1)) * 768;
    if (t < 128){
        atomicAdd(&stats[l*128 + t], lsum[t]);
        atomicAdd(&stats[384 + l*128 + t], lsq[t]);
    }
}

// ---- reduce 64 stat partials -> BN constants A,B --------------------------
struct BArgs { const float* g[3]; const float* b[3]; };

__global__ void k_bn(BArgs ba, const float* statsP, float* bnAB, int Nn){
    int t = threadIdx.x;
    if (t >= 384) return;
    float su = 0.f, sq = 0.f;
    for (int k = 0; k < NSTAT; ++k){
        su += statsP[(size_t)k * 768 + t];
        sq += statsP[(size_t)k * 768 + 384 + t];
    }
    int l = t >> 7;
    float mu = su / (float)Nn;
    float var = fmaxf(sq / (float)Nn - mu*mu, 0.f);
    float inv = rsqrtf(var + 1e-5f);
    float g = ba.g[l][t & 127], b = ba.b[l][t & 127];
    bnAB[t] = g * inv;
    bnAB[384 + t] = b - mu * g * inv;
}

// ---- fused final: ent output | relation update ----------------------------
__global__ __launch_bounds__(256)
void k_fin(const unsigned short* Pb, const float* bnAB,
           const float* ent, const float* relW, const float* relb,
           const float* rel, const int* heads, const int* tails,
           float* outp, int Nn, int npad, int FB, int Sp)
{
    int t = threadIdx.x, bid = blockIdx.x;
    if (bid < FB){
        __shared__ float sAB[768];
        for (int i = t; i < 768; i += 256) sAB[i] = bnAB[i];
        __syncthreads();
        int gid = bid * 256 + t;
        if (gid >= Nn * 32) return;
        int v = gid >> 5, q4 = (gid & 31) * 4;
        size_t pst = (size_t)npad * DN;
        size_t pb = (size_t)v * DN + q4;
        ushort4 p0 = *(const ushort4*)(Pb + pb);
        ushort4 p1 = *(const ushort4*)(Pb + pst + pb);
        ushort4 p2 = *(const ushort4*)(Pb + 2*pst + pb);
        float4 e4 = *(const float4*)(ent + (size_t)v * DN + q4);
        float pe[4] = { e4.x, e4.y, e4.z, e4.w };
        unsigned short pu[3][4] = { {p0.x, p0.y, p0.z, p0.w},
                                    {p1.x, p1.y, p1.z, p1.w},
                                    {p2.x, p2.y, p2.z, p2.w} };
        float o[4];
        #pragma unroll
        for (int q = 0; q < 4; ++q){
            float s = pe[q];
            #pragma unroll
            for (int l = 0; l < 3; ++l){
                int jj = l*128 + q4 + q;
                s += tanh_(sAB[jj] * bfs(pu[l][q]) + sAB[384 + jj]);
            }
            o[q] = s;
        }
        float4 ov = { o[0], o[1], o[2], o[3] };
        *(float4*)(outp + (size_t)v * DN + q4) = ov;
    } else {
        __shared__ float mp[256];
        int rr = (bid - FB) * 2 + (t >> 7);
        int j = t & 127;
        float acc = 0.f;
        for (int s = 0; s < Sp; ++s){
            int p = rr * Sp + s;
            acc += ent[(size_t)tails[p] * DN + j] - ent[(size_t)heads[p] * DN + j];
        }
        mp[t] = acc / (float)Sp;
        __syncthreads();
        float dot = relb[j];
        const float4* wr = (const float4*)(relW + (size_t)j * DN);
        const float* mpr = mp + (t >> 7) * 128;
        #pragma unroll 8
        for (int kb = 0; kb < 32; ++kb){
            float4 w = wr[kb];
            dot += mpr[kb*4+0]*w.x + mpr[kb*4+1]*w.y + mpr[kb*4+2]*w.z + mpr[kb*4+3]*w.w;
        }
        outp[(size_t)Nn * DN + (size_t)rr * DN + j] = rel[(size_t)rr * DN + j] + tanh_(dot);
    }
}

// ---------------------------------------------------------------------------
extern "C" void kernel_launch(void* const* d_in, const int* in_sizes, int n_in,
                              void* d_out, int out_size, void* d_ws, size_t ws_size,
                              hipStream_t stream)
{
    const float* entf = (const float*)d_in[0];
    const float* relf = (const float*)d_in[1];
    const float* eWo = (const float*)d_in[2];  const float* ebo = (const float*)d_in[3];
    const float* eWi = (const float*)d_in[4];  const float* ebi = (const float*)d_in[5];
    const float* eg  = (const float*)d_in[6];  const float* eb  = (const float*)d_in[7];
    const float* nWo = (const float*)d_in[8];  const float* nbo = (const float*)d_in[9];
    const float* nWi = (const float*)d_in[10]; const float* nbi = (const float*)d_in[11];
    const float* ng  = (const float*)d_in[12]; const float* nb_ = (const float*)d_in[13];
    const float* cWo = (const float*)d_in[14]; const float* cbo = (const float*)d_in[15];
    const float* cWi = (const float*)d_in[16]; const float* cbi = (const float*)d_in[17];
    const float* cg  = (const float*)d_in[18]; const float* cb  = (const float*)d_in[19];
    const float* relWs  = (const float*)d_in[20];
    const float* relb32 = (const float*)d_in[21];
    const int* srcp   = (const int*)d_in[22];
    const int* dstp   = (const int*)d_in[23];
    const int* etyp   = (const int*)d_in[24];
    const int* headsp = (const int*)d_in[25];
    const int* tailsp = (const int*)d_in[26];
    const unsigned char* mask8 = (const unsigned char*)d_in[28];   // in_mask

    int Nn = in_sizes[0] / DN;
    int Rr = in_sizes[1] / DN;
    int E  = in_sizes[22];
    int Pp = in_sizes[25];
    int Sp = Pp / Rr;
    int npad = ((Nn + 255) / 256) * 256;
    int nsb = npad / 256;

    char* w = (char*)d_ws; size_t off = 0;
    auto carve = [&](size_t b) -> void* {
        void* p = w + off; off = (off + b + 255) & ~(size_t)255; return p;
    };
    // zero-region first (flag | counts | statsP), one memset covers all
    int*   flag   = (int*)  carve(4);
    int*   counts = (int*)  carve((size_t)npad * 4);
    float* statsP = (float*)carve((size_t)NSTAT * 768 * 4);
    size_t zlen = off;
    int*   rowst  = (int*)  carve((size_t)(npad + 1) * 4);
    int*   cursor = (int*)  carve((size_t)npad * 4);
    uint32_t* epack = (uint32_t*)carve((size_t)E * 4);
    int*   bsums  = (int*)  carve(1024 * 4);
    unsigned short* wcv = (unsigned short*)carve((size_t)6 * 16384 * 2);
    short* Sb     = (short*)carve((size_t)6 * npad * DN * 2);
    unsigned short* Pb = (unsigned short*)carve((size_t)3 * npad * DN * 2);
    float* Rv     = (float*)carve((size_t)6 * npad * 4);
    float* bnAB   = (float*)carve(768 * 4);

    hipMemsetAsync(d_ws, 0, zlen, stream);

    WC wc; wc.src[0] = eWi; wc.src[1] = nWi; wc.src[2] = cWi;
           wc.src[3] = eWo; wc.src[4] = nWo; wc.src[5] = cWo;
    int nwords = 4096;
    k_pre<<<(E + 255) / 256, 256, 0, stream>>>(dstp, counts, (const uint32_t*)mask8,
                                               nwords, flag, wc, wcv, E);
    k_scan_a<<<nsb, 256, 0, stream>>>(counts, bsums);
    k_scan_bc<<<nsb, 256, 0, stream>>>(counts, bsums, nsb, rowst, cursor, npad, E);
    k_scatter<<<(E + 255) / 256, 256, 0, stream>>>(dstp, srcp, etyp, mask8, flag,
                                                   cursor, epack, E);

    k_node<<<npad / 4, 256, 0, stream>>>((const float4*)entf, (const float4*)relf,
                                         epack, rowst, (uint32_t*)Sb, Rv, Nn, npad);

    GArgs ga;
    ga.Wi[0] = (const short*)(wcv + 0*16384);
    ga.Wi[1] = (const short*)(wcv + 1*16384);
    ga.Wi[2] = (const short*)(wcv + 2*16384);
    ga.Wo[0] = (const short*)(wcv + 3*16384);
    ga.Wo[1] = (const short*)(wcv + 4*16384);
    ga.Wo[2] = (const short*)(wcv + 5*16384);
    ga.bi[0] = ebi; ga.bi[1] = nbi; ga.bi[2] = cbi;
    ga.bo[0] = ebo; ga.bo[1] = nbo; ga.bo[2] = cbo;
    k_gemm<<<dim3(npad / 64, 3), 256, 0, stream>>>(ga, Sb, Rv, Pb, statsP, npad, Nn);

    BArgs ba;
    ba.g[0] = eg; ba.g[1] = ng; ba.g[2] = cg;
    ba.b[0] = eb; ba.b[1] = nb_; ba.b[2] = cb;
    k_bn<<<1, 384, 0, stream>>>(ba, statsP, bnAB, Nn);

    int FB = (Nn * 32 + 255) / 256;
    int grid = FB + Rr / 2;
    k_fin<<<grid, 256, 0, stream>>>(Pb, bnAB, entf, relWs, relb32, relf,
                                    headsp, tailsp, (float*)d_out, Nn, npad, FB, Sp);
}

// Round 7
// 361.737 us; speedup vs baseline: 1.1606x; 1.0835x over previous
//
#include <hip/hip_runtime.h>
#include <stdint.h>

#define DN 128
#define NSTAT 64

typedef short s16x8 __attribute__((ext_vector_type(8)));
typedef float f32x4 __attribute__((ext_vector_type(4)));
typedef float f32x8 __attribute__((ext_vector_type(8)));

__device__ __forceinline__ float bfs(unsigned short u){ return __uint_as_float(((uint32_t)u) << 16); }
__device__ __forceinline__ uint32_t f2bf(float f){
    uint32_t x = __float_as_uint(f);
    return (x + 0x7FFFu + ((x >> 16) & 1u)) >> 16;   // RTNE
}
__device__ __forceinline__ uint32_t packbf(float a, float b){ return f2bf(a) | (f2bf(b) << 16); }
__device__ __forceinline__ float tanh_(float x){
    float e = __expf(2.0f * x);
    return 1.0f - 2.0f / (e + 1.0f);
}

// ---- fused: dst histogram + mask-format detect + weight f32->bf16 ---------
struct WC { const float* src[6]; };
__global__ void k_pre(const int* dst, int* counts,
                      const uint32_t* maskw, int nwords, int* flag,
                      WC wc, unsigned short* wcv, int E){
    int gid = blockIdx.x * 256 + threadIdx.x;
    if (gid < E) atomicAdd(&counts[dst[gid]], 1);
    if (gid < nwords && maskw[gid] > 1u) atomicOr(flag, 1);
    if (gid < 6 * 16384){
        int m = gid >> 14, o = gid & 16383;
        wcv[(size_t)m * 16384 + o] = (unsigned short)f2bf(wc.src[m][o]);
    }
}

// ---- CSR scan: per-256-chunk sums -----------------------------------------
__global__ void k_scan_a(const int* counts, int* bsums){
    int t = threadIdx.x;
    int s = counts[blockIdx.x * 256 + t];
    #pragma unroll
    for (int o = 32; o; o >>= 1) s += __shfl_xor(s, o);
    __shared__ int wsum[4];
    if ((t & 63) == 0) wsum[t >> 6] = s;
    __syncthreads();
    if (t == 0) bsums[blockIdx.x] = wsum[0] + wsum[1] + wsum[2] + wsum[3];
}

// ---- CSR scan: per-block prefix over bsums + local scan -------------------
__global__ void k_scan_bc(const int* counts, const int* bsums, int nsb,
                          int* rowst, int* cursor, int npad, int E){
    __shared__ int pref;
    __shared__ int wsum[4];
    __shared__ int buf[256];
    int t = threadIdx.x, bid = blockIdx.x;
    int s = (t < bid && t < nsb) ? bsums[t] : 0;
    #pragma unroll
    for (int o = 32; o; o >>= 1) s += __shfl_xor(s, o);
    if ((t & 63) == 0) wsum[t >> 6] = s;
    __syncthreads();
    if (t == 0) pref = wsum[0] + wsum[1] + wsum[2] + wsum[3];
    int i = bid * 256 + t;
    int c = counts[i];
    buf[t] = c;
    __syncthreads();
    for (int o = 1; o < 256; o <<= 1){
        int add = (t >= o) ? buf[t - o] : 0;
        __syncthreads();
        buf[t] += add;
        __syncthreads();
    }
    int rsv = buf[t] - c + pref;
    rowst[i] = rsv; cursor[i] = rsv;
    if (i == npad - 1) rowst[npad] = E;
}

// ---- scatter edges into CSR order as packed records -----------------------
// epack = src[31:16] | etype[15:1] | mask[0]
__global__ void k_scatter(const int* dst, const int* src, const int* etype,
                          const unsigned char* mask8, const int* flagp,
                          int* cursor, uint32_t* epack, int E){
    int e = blockIdx.x * blockDim.x + threadIdx.x;
    if (e >= E) return;
    int bmode = *flagp;
    int mk = bmode ? (int)mask8[e] : ((const int*)mask8)[e];
    int pos = atomicAdd(&cursor[dst[e]], 1);
    epack[pos] = ((uint32_t)src[e] << 16) | ((uint32_t)etype[e] << 1) | (uint32_t)(mk != 0);
}

// ---- per-node fused 3-layer online softmax, 4 edges per wave --------------
// 4 groups of 16 lanes; group g handles edges 4j+g; lane sl holds elements
// sl*8..sl*8+7 (float8). Defer-max (THR=20): rescale only when the group max
// actually grows past the lag window. Padded slots force p=-1e38 (max-safe).
// 4 group-streams merged by 2 butterfly-merge stages (xor 16, 32).
__global__ __launch_bounds__(256)
void k_node(const f32x8* ent8, const f32x8* rel8,
            const uint32_t* epack, const int* rowst,
            uint32_t* Sw, float* Rv, int Nn, int npad)
{
    int t = threadIdx.x, lane = t & 63, wv = t >> 6;
    int v = blockIdx.x * 4 + wv;
    if (v >= npad) return;
    int sl = lane & 15, grp = lane >> 4;

    f32x8 d8 = {0,0,0,0,0,0,0,0};
    int deg = 0, rs = 0;
    if (v < Nn){
        rs = rowst[v]; deg = rowst[v + 1] - rs;
        d8 = ent8[(size_t)v * 16 + sl];
    }
    float m0 = -1e30f, m1 = -1e30f, m2 = -1e30f;
    float si0 = 0, si1 = 0, si2 = 0, so0 = 0, so1 = 0, so2 = 0;
    f32x8 aI0 = {0,0,0,0,0,0,0,0}, aO0 = {0,0,0,0,0,0,0,0};
    f32x8 aI1 = {0,0,0,0,0,0,0,0}, aO1 = {0,0,0,0,0,0,0,0};
    f32x8 aI2 = {0,0,0,0,0,0,0,0}, aO2 = {0,0,0,0,0,0,0,0};

    for (int base = 0; base < deg; base += 64){
        int nb = min(64, deg - base);
        uint32_t pk = 0;
        if (lane < nb) pk = epack[rs + base + lane];
        int ngrp = (nb + 3) >> 2;
        for (int j = 0; j < ngrp; ++j){
            int ei = 4 * j + grp;
            uint32_t w = (uint32_t)__shfl((int)pk, ei);
            int sj = (int)(w >> 16);
            int tj = (int)((w >> 1) & 0x7FFF);
            float mk = (float)(w & 1u);
            f32x8 s8 = ent8[(size_t)sj * 16 + sl];
            f32x8 r8 = rel8[(size_t)tj * 16 + sl];
            f32x8 c8;
            #pragma unroll
            for (int q = 0; q < 8; ++q) c8[q] = s8[q] * r8[q];
            float p0 = 0.f, p1 = 0.f, p2 = 0.f;
            #pragma unroll
            for (int q = 0; q < 8; ++q){
                p0 += r8[q] * d8[q];
                p1 += s8[q] * d8[q];
                p2 += c8[q] * d8[q];
            }
            #pragma unroll
            for (int o = 1; o < 16; o <<= 1){
                p0 += __shfl_xor(p0, o);
                p1 += __shfl_xor(p1, o);
                p2 += __shfl_xor(p2, o);
            }
            if (ei >= nb){ p0 = -1e38f; p1 = -1e38f; p2 = -1e38f; }
            // layer 0 (message = rel row)
            {
                if (__any(p0 > m0 + 20.f)){
                    float nm = fmaxf(m0, p0);
                    float f = __expf(m0 - nm);
                    si0 *= f; so0 *= f;
                    #pragma unroll
                    for (int q = 0; q < 8; ++q){ aI0[q] *= f; aO0[q] *= f; }
                    m0 = nm;
                }
                float e = __expf(p0 - m0);
                float ein = e * mk, eout = e - ein;
                si0 += ein; so0 += eout;
                #pragma unroll
                for (int q = 0; q < 8; ++q){ aI0[q] += ein * r8[q]; aO0[q] += eout * r8[q]; }
            }
            // layer 1 (message = src row)
            {
                if (__any(p1 > m1 + 20.f)){
                    float nm = fmaxf(m1, p1);
                    float f = __expf(m1 - nm);
                    si1 *= f; so1 *= f;
                    #pragma unroll
                    for (int q = 0; q < 8; ++q){ aI1[q] *= f; aO1[q] *= f; }
                    m1 = nm;
                }
                float e = __expf(p1 - m1);
                float ein = e * mk, eout = e - ein;
                si1 += ein; so1 += eout;
                #pragma unroll
                for (int q = 0; q < 8; ++q){ aI1[q] += ein * s8[q]; aO1[q] += eout * s8[q]; }
            }
            // layer 2 (message = src*rel row)
            {
                if (__any(p2 > m2 + 20.f)){
                    float nm = fmaxf(m2, p2);
                    float f = __expf(m2 - nm);
                    si2 *= f; so2 *= f;
                    #pragma unroll
                    for (int q = 0; q < 8; ++q){ aI2[q] *= f; aO2[q] *= f; }
                    m2 = nm;
                }
                float e = __expf(p2 - m2);
                float ein = e * mk, eout = e - ein;
                si2 += ein; so2 += eout;
                #pragma unroll
                for (int q = 0; q < 8; ++q){ aI2[q] += ein * c8[q]; aO2[q] += eout * c8[q]; }
            }
        }
    }

    // merge the 4 group-streams: butterfly-merge stages xor 16 then xor 32
#define MRG8(OFF, m, si, so, aI, aO) {                                     \
        float mo = __shfl_xor(m, OFF);                                     \
        float nm = fmaxf(m, mo);                                           \
        float f = __expf(m - nm);                                          \
        si *= f; so *= f;                                                  \
        _Pragma("unroll")                                                  \
        for (int q = 0; q < 8; ++q){ aI[q] *= f; aO[q] *= f; }             \
        si += __shfl_xor(si, OFF);                                         \
        so += __shfl_xor(so, OFF);                                         \
        _Pragma("unroll")                                                  \
        for (int q = 0; q < 8; ++q){                                       \
            aI[q] += __shfl_xor(aI[q], OFF);                               \
            aO[q] += __shfl_xor(aO[q], OFF);                               \
        }                                                                  \
        m = nm; }
    MRG8(16, m0, si0, so0, aI0, aO0)
    MRG8(16, m1, si1, so1, aI1, aO1)
    MRG8(16, m2, si2, so2, aI2, aO2)
    MRG8(32, m0, si0, so0, aI0, aO0)
    MRG8(32, m1, si1, so1, aI1, aO1)
    MRG8(32, m2, si2, so2, aI2, aO2)
#undef MRG8

    if (lane < 16){
        uint4* S4 = (uint4*)Sw;
        size_t s4 = (size_t)npad * 16;
        size_t wi = (size_t)v * 16 + sl;
        float st, inv;
#define PK8(A, I) make_uint4(packbf(A[0]*I, A[1]*I), packbf(A[2]*I, A[3]*I), \
                             packbf(A[4]*I, A[5]*I), packbf(A[6]*I, A[7]*I))
        st = si0 + so0; inv = st > 0.f ? 1.f / st : 0.f;
        S4[0*s4 + wi] = PK8(aI0, inv);
        S4[1*s4 + wi] = PK8(aO0, inv);
        float ri0 = si0*inv, ro0 = so0*inv;
        st = si1 + so1; inv = st > 0.f ? 1.f / st : 0.f;
        S4[2*s4 + wi] = PK8(aI1, inv);
        S4[3*s4 + wi] = PK8(aO1, inv);
        float ri1 = si1*inv, ro1 = so1*inv;
        st = si2 + so2; inv = st > 0.f ? 1.f / st : 0.f;
        S4[4*s4 + wi] = PK8(aI2, inv);
        S4[5*s4 + wi] = PK8(aO2, inv);
        float ri2 = si2*inv, ro2 = so2*inv;
#undef PK8
        if (sl == 0){
            Rv[0*(size_t)npad + v] = ri0; Rv[1*(size_t)npad + v] = ro0;
            Rv[2*(size_t)npad + v] = ri1; Rv[3*(size_t)npad + v] = ro1;
            Rv[4*(size_t)npad + v] = ri2; Rv[5*(size_t)npad + v] = ro2;
        }
    }
}

// ---- dense [N x 128] @ W^T GEMM (MFMA) + bias + col stats -----------------
// Each wave owns 64 rows (4 row-tiles resident in VGPRs); ct-loop reloads
// only the 8 weight fragments per iteration (reused across 4 row-tiles).
// launch_bounds(256,1) frees the register allocator (~220 VGPR, 8 waves/CU).
struct GArgs {
    const short* Wi[3]; const short* Wo[3];
    const float* bi[3]; const float* bo[3];
};

__global__ __launch_bounds__(256, 1)
void k_gemm(GArgs ga, const short* Sb, const float* Rv, unsigned short* P,
            float* statsP, int npad, int Nn)
{
    __shared__ float lsum[128], lsq[128];
    int t = threadIdx.x;
    if (t < 128){ lsum[t] = 0.f; lsq[t] = 0.f; }
    __syncthreads();
    int l = blockIdx.y;
    int lane = t & 63, wv = t >> 6;
    int lo = lane & 15, hi = lane >> 4;
    int wr0 = blockIdx.x * 256 + wv * 64;      // wave's 64 rows
    size_t sstride = (size_t)npad * DN;
    const short* Sin  = Sb + (size_t)(2*l)   * sstride;
    const short* Sout = Sb + (size_t)(2*l+1) * sstride;
    const short* Wi = ga.Wi[l]; const short* Wo = ga.Wo[l];

    s16x8 ain[4][4], aout[4][4];               // [row-tile][kb] : 128 VGPR
    #pragma unroll
    for (int rt = 0; rt < 4; ++rt)
        #pragma unroll
        for (int kb = 0; kb < 4; ++kb){
            size_t o = (size_t)(wr0 + rt*16 + lo) * DN + kb*32 + hi*8;
            ain[rt][kb]  = *(const s16x8*)(Sin + o);
            aout[rt][kb] = *(const s16x8*)(Sout + o);
        }
    float rin[4][4], rout[4][4];
    const float* RvI = Rv + (size_t)(2*l)   * npad;
    const float* RvO = Rv + (size_t)(2*l+1) * npad;
    #pragma unroll
    for (int rt = 0; rt < 4; ++rt)
        #pragma unroll
        for (int rg = 0; rg < 4; ++rg){
            int vr = wr0 + rt*16 + hi*4 + rg;
            rin[rt][rg] = RvI[vr]; rout[rt][rg] = RvO[vr];
        }
    unsigned short* Pl = P + (size_t)l * sstride;

    #pragma unroll
    for (int ct = 0; ct < 8; ++ct){
        s16x8 bwi[4], bwo[4];
        #pragma unroll
        for (int kb = 0; kb < 4; ++kb){
            size_t wo_ = (size_t)(ct*16 + lo) * DN + kb*32 + hi*8;
            bwi[kb] = *(const s16x8*)(Wi + wo_);
            bwo[kb] = *(const s16x8*)(Wo + wo_);
        }
        int j = ct*16 + lo;
        float biv = ga.bi[l][j], bov = ga.bo[l][j];
        float cs = 0.f, cq = 0.f;
        #pragma unroll
        for (int rt = 0; rt < 4; ++rt){
            f32x4 acc = {0.f, 0.f, 0.f, 0.f};
            #pragma unroll
            for (int kb = 0; kb < 4; ++kb){
                acc = __builtin_amdgcn_mfma_f32_16x16x32_bf16(ain[rt][kb], bwi[kb], acc, 0, 0, 0);
                acc = __builtin_amdgcn_mfma_f32_16x16x32_bf16(aout[rt][kb], bwo[kb], acc, 0, 0, 0);
            }
            #pragma unroll
            for (int rg = 0; rg < 4; ++rg){
                float pv = acc[rg] + rin[rt][rg]*biv + rout[rt][rg]*bov;
                Pl[(size_t)(wr0 + rt*16 + hi*4 + rg) * DN + j] = (unsigned short)f2bf(pv);
                cs += pv; cq += pv*pv;
            }
        }
        cs += __shfl_xor(cs, 16); cs += __shfl_xor(cs, 32);
        cq += __shfl_xor(cq, 16); cq += __shfl_xor(cq, 32);
        if (lane < 16){ atomicAdd(&lsum[j], cs); atomicAdd(&lsq[j], cq); }
    }
    __syncthreads();
    float* stats = statsP + (size_t)((blockIdx.x ^ (blockIdx.y << 4)) & (NSTAT-1)) * 768;
    if (t < 128){
        atomicAdd(&stats[l*128 + t], lsum[t]);
        atomicAdd(&stats[384 + l*128 + t], lsq[t]);
    }
}

// ---- reduce stat partials -> BN constants A,B -----------------------------
struct BArgs { const float* g[3]; const float* b[3]; };

__global__ void k_bn(BArgs ba, const float* statsP, float* bnAB, int Nn){
    int t = threadIdx.x;
    if (t >= 384) return;
    float su = 0.f, sq = 0.f;
    for (int k = 0; k < NSTAT; ++k){
        su += statsP[(size_t)k * 768 + t];
        sq += statsP[(size_t)k * 768 + 384 + t];
    }
    int l = t >> 7;
    float mu = su / (float)Nn;
    float var = fmaxf(sq / (float)Nn - mu*mu, 0.f);
    float inv = rsqrtf(var + 1e-5f);
    float g = ba.g[l][t & 127], b = ba.b[l][t & 127];
    bnAB[t] = g * inv;
    bnAB[384 + t] = b - mu * g * inv;
}

// ---- fused final: ent output | relation update ----------------------------
__global__ __launch_bounds__(256)
void k_fin(const unsigned short* Pb, const float* bnAB,
           const float* ent, const float* relW, const float* relb,
           const float* rel, const int* heads, const int* tails,
           float* outp, int Nn, int npad, int FB, int Sp)
{
    int t = threadIdx.x, bid = blockIdx.x;
    if (bid < FB){
        __shared__ float sAB[768];
        for (int i = t; i < 768; i += 256) sAB[i] = bnAB[i];
        __syncthreads();
        int gid = bid * 256 + t;
        if (gid >= Nn * 32) return;
        int v = gid >> 5, q4 = (gid & 31) * 4;
        size_t pst = (size_t)npad * DN;
        size_t pb = (size_t)v * DN + q4;
        ushort4 p0 = *(const ushort4*)(Pb + pb);
        ushort4 p1 = *(const ushort4*)(Pb + pst + pb);
        ushort4 p2 = *(const ushort4*)(Pb + 2*pst + pb);
        float4 e4 = *(const float4*)(ent + (size_t)v * DN + q4);
        float pe[4] = { e4.x, e4.y, e4.z, e4.w };
        unsigned short pu[3][4] = { {p0.x, p0.y, p0.z, p0.w},
                                    {p1.x, p1.y, p1.z, p1.w},
                                    {p2.x, p2.y, p2.z, p2.w} };
        float o[4];
        #pragma unroll
        for (int q = 0; q < 4; ++q){
            float s = pe[q];
            #pragma unroll
            for (int l = 0; l < 3; ++l){
                int jj = l*128 + q4 + q;
                s += tanh_(sAB[jj] * bfs(pu[l][q]) + sAB[384 + jj]);
            }
            o[q] = s;
        }
        float4 ov = { o[0], o[1], o[2], o[3] };
        *(float4*)(outp + (size_t)v * DN + q4) = ov;
    } else {
        __shared__ float mp[256];
        int rr = (bid - FB) * 2 + (t >> 7);
        int j = t & 127;
        float acc = 0.f;
        for (int s = 0; s < Sp; ++s){
            int p = rr * Sp + s;
            acc += ent[(size_t)tails[p] * DN + j] - ent[(size_t)heads[p] * DN + j];
        }
        mp[t] = acc / (float)Sp;
        __syncthreads();
        float dot = relb[j];
        const float4* wr = (const float4*)(relW + (size_t)j * DN);
        const float* mpr = mp + (t >> 7) * 128;
        #pragma unroll 8
        for (int kb = 0; kb < 32; ++kb){
            float4 w = wr[kb];
            dot += mpr[kb*4+0]*w.x + mpr[kb*4+1]*w.y + mpr[kb*4+2]*w.z + mpr[kb*4+3]*w.w;
        }
        outp[(size_t)Nn * DN + (size_t)rr * DN + j] = rel[(size_t)rr * DN + j] + tanh_(dot);
    }
}

// ---------------------------------------------------------------------------
extern "C" void kernel_launch(void* const* d_in, const int* in_sizes, int n_in,
                              void* d_out, int out_size, void* d_ws, size_t ws_size,
                              hipStream_t stream)
{
    const float* entf = (const float*)d_in[0];
    const float* relf = (const float*)d_in[1];
    const float* eWo = (const float*)d_in[2];  const float* ebo = (const float*)d_in[3];
    const float* eWi = (const float*)d_in[4];  const float* ebi = (const float*)d_in[5];
    const float* eg  = (const float*)d_in[6];  const float* eb  = (const float*)d_in[7];
    const float* nWo = (const float*)d_in[8];  const float* nbo = (const float*)d_in[9];
    const float* nWi = (const float*)d_in[10]; const float* nbi = (const float*)d_in[11];
    const float* ng  = (const float*)d_in[12]; const float* nb_ = (const float*)d_in[13];
    const float* cWo = (const float*)d_in[14]; const float* cbo = (const float*)d_in[15];
    const float* cWi = (const float*)d_in[16]; const float* cbi = (const float*)d_in[17];
    const float* cg  = (const float*)d_in[18]; const float* cb  = (const float*)d_in[19];
    const float* relWs  = (const float*)d_in[20];
    const float* relb32 = (const float*)d_in[21];
    const int* srcp   = (const int*)d_in[22];
    const int* dstp   = (const int*)d_in[23];
    const int* etyp   = (const int*)d_in[24];
    const int* headsp = (const int*)d_in[25];
    const int* tailsp = (const int*)d_in[26];
    const unsigned char* mask8 = (const unsigned char*)d_in[28];   // in_mask

    int Nn = in_sizes[0] / DN;
    int Rr = in_sizes[1] / DN;
    int E  = in_sizes[22];
    int Pp = in_sizes[25];
    int Sp = Pp / Rr;
    int npad = ((Nn + 255) / 256) * 256;
    int nsb = npad / 256;

    char* w = (char*)d_ws; size_t off = 0;
    auto carve = [&](size_t b) -> void* {
        void* p = w + off; off = (off + b + 255) & ~(size_t)255; return p;
    };
    // zero-region first (flag | counts | statsP), one memset covers all
    int*   flag   = (int*)  carve(4);
    int*   counts = (int*)  carve((size_t)npad * 4);
    float* statsP = (float*)carve((size_t)NSTAT * 768 * 4);
    size_t zlen = off;
    int*   rowst  = (int*)  carve((size_t)(npad + 1) * 4);
    int*   cursor = (int*)  carve((size_t)npad * 4);
    uint32_t* epack = (uint32_t*)carve((size_t)E * 4);
    int*   bsums  = (int*)  carve(1024 * 4);
    unsigned short* wcv = (unsigned short*)carve((size_t)6 * 16384 * 2);
    short* Sb     = (short*)carve((size_t)6 * npad * DN * 2);
    unsigned short* Pb = (unsigned short*)carve((size_t)3 * npad * DN * 2);
    float* Rv     = (float*)carve((size_t)6 * npad * 4);
    float* bnAB   = (float*)carve(768 * 4);

    hipMemsetAsync(d_ws, 0, zlen, stream);

    WC wc; wc.src[0] = eWi; wc.src[1] = nWi; wc.src[2] = cWi;
           wc.src[3] = eWo; wc.src[4] = nWo; wc.src[5] = cWo;
    int nwords = 4096;
    k_pre<<<(E + 255) / 256, 256, 0, stream>>>(dstp, counts, (const uint32_t*)mask8,
                                               nwords, flag, wc, wcv, E);
    k_scan_a<<<nsb, 256, 0, stream>>>(counts, bsums);
    k_scan_bc<<<nsb, 256, 0, stream>>>(counts, bsums, nsb, rowst, cursor, npad, E);
    k_scatter<<<(E + 255) / 256, 256, 0, stream>>>(dstp, srcp, etyp, mask8, flag,
                                                   cursor, epack, E);

    k_node<<<npad / 4, 256, 0, stream>>>((const f32x8*)entf, (const f32x8*)relf,
                                         epack, rowst, (uint32_t*)Sb, Rv, Nn, npad);

    GArgs ga;
    ga.Wi[0] = (const short*)(wcv + 0*16384);
    ga.Wi[1] = (const short*)(wcv + 1*16384);
    ga.Wi[2] = (const short*)(wcv + 2*16384);
    ga.Wo[0] = (const short*)(wcv + 3*16384);
    ga.Wo[1] = (const short*)(wcv + 4*16384);
    ga.Wo[2] = (const short*)(wcv + 5*16384);
    ga.bi[0] = ebi; ga.bi[1] = nbi; ga.bi[2] = cbi;
    ga.bo[0] = ebo; ga.bo[1] = nbo; ga.bo[2] = cbo;
    k_gemm<<<dim3(npad / 256, 3), 256, 0, stream>>>(ga, Sb, Rv, Pb, statsP, npad, Nn);

    BArgs ba;
    ba.g[0] = eg; ba.g[1] = ng; ba.g[2] = cg;
    ba.b[0] = eb; ba.b[1] = nb_; ba.b[2] = cb;
    k_bn<<<1, 384, 0, stream>>>(ba, statsP, bnAB, Nn);

    int FB = (Nn * 32 + 255) / 256;
    int grid = FB + Rr / 2;
    k_fin<<<grid, 256, 0, stream>>>(Pb, bnAB, entf, relWs, relb32, relf,
                                    headsp, tailsp, (float*)d_out, Nn, npad, FB, Sp);
}

// Round 9
// 336.264 us; speedup vs baseline: 1.2485x; 1.0758x over previous
//
#include <hip/hip_runtime.h>
#include <stdint.h>

#define DN 128
#define NSTAT 64

typedef short s16x8 __attribute__((ext_vector_type(8)));
typedef float f32x4 __attribute__((ext_vector_type(4)));

__device__ __forceinline__ float bfs(unsigned short u){ return __uint_as_float(((uint32_t)u) << 16); }
__device__ __forceinline__ uint32_t f2bf(float f){
    uint32_t x = __float_as_uint(f);
    return (x + 0x7FFFu + ((x >> 16) & 1u)) >> 16;   // RTNE
}
__device__ __forceinline__ uint32_t packbf(float a, float b){ return f2bf(a) | (f2bf(b) << 16); }
__device__ __forceinline__ float tanh_(float x){
    float e = __expf(2.0f * x);
    return 1.0f - 2.0f / (e + 1.0f);
}

// ---- fused: dst histogram + mask-format detect + weight f32->bf16 ---------
struct WC { const float* src[6]; };
__global__ void k_pre(const int* dst, int* counts,
                      const uint32_t* maskw, int nwords, int* flag,
                      WC wc, unsigned short* wcv, int E){
    int gid = blockIdx.x * 256 + threadIdx.x;
    if (gid < E) atomicAdd(&counts[dst[gid]], 1);
    if (gid < nwords && maskw[gid] > 1u) atomicOr(flag, 1);
    if (gid < 6 * 16384){
        int m = gid >> 14, o = gid & 16383;
        wcv[(size_t)m * 16384 + o] = (unsigned short)f2bf(wc.src[m][o]);
    }
}

// ---- CSR scan: per-256-chunk sums -----------------------------------------
__global__ void k_scan_a(const int* counts, int* bsums){
    int t = threadIdx.x;
    int s = counts[blockIdx.x * 256 + t];
    #pragma unroll
    for (int o = 32; o; o >>= 1) s += __shfl_xor(s, o);
    __shared__ int wsum[4];
    if ((t & 63) == 0) wsum[t >> 6] = s;
    __syncthreads();
    if (t == 0) bsums[blockIdx.x] = wsum[0] + wsum[1] + wsum[2] + wsum[3];
}

// ---- CSR scan: per-block prefix over bsums + local scan -------------------
__global__ void k_scan_bc(const int* counts, const int* bsums, int nsb,
                          int* rowst, int* cursor, int npad, int E){
    __shared__ int pref;
    __shared__ int wsum[4];
    __shared__ int buf[256];
    int t = threadIdx.x, bid = blockIdx.x;
    int s = (t < bid && t < nsb) ? bsums[t] : 0;
    #pragma unroll
    for (int o = 32; o; o >>= 1) s += __shfl_xor(s, o);
    if ((t & 63) == 0) wsum[t >> 6] = s;
    __syncthreads();
    if (t == 0) pref = wsum[0] + wsum[1] + wsum[2] + wsum[3];
    int i = bid * 256 + t;
    int c = counts[i];
    buf[t] = c;
    __syncthreads();
    for (int o = 1; o < 256; o <<= 1){
        int add = (t >= o) ? buf[t - o] : 0;
        __syncthreads();
        buf[t] += add;
        __syncthreads();
    }
    int rsv = buf[t] - c + pref;
    rowst[i] = rsv; cursor[i] = rsv;
    if (i == npad - 1) rowst[npad] = E;
}

// ---- scatter edges into CSR order as packed records -----------------------
// epack = src[31:16] | etype[15:1] | mask[0]
__global__ void k_scatter(const int* dst, const int* src, const int* etype,
                          const unsigned char* mask8, const int* flagp,
                          int* cursor, uint32_t* epack, int E){
    int e = blockIdx.x * blockDim.x + threadIdx.x;
    if (e >= E) return;
    int bmode = *flagp;
    int mk = bmode ? (int)mask8[e] : ((const int*)mask8)[e];
    int pos = atomicAdd(&cursor[dst[e]], 1);
    epack[pos] = ((uint32_t)src[e] << 16) | ((uint32_t)etype[e] << 1) | (uint32_t)(mk != 0);
}

// ---- per-node fused 3-layer online softmax, 2 edges per wave --------------
// lanes 0-31 = even edges, lanes 32-63 = odd edges; lane sl holds elements
// sl*4..sl*4+3 (f32 gathers — exact). Defer-max THR=20 (validated r7) skips
// the rescale while the max stays in the lag window. Depth-1 prefetch of the
// next pair's rows hides L2/LLC gather latency under the softmax chain.
// Padded slots force p=-1e38 (contribute exp(-huge)=0, never touch the max).
__global__ __launch_bounds__(256)
void k_node(const float4* ent4, const float4* rel4,
            const uint32_t* epack, const int* rowst,
            uint32_t* Sw, float* Rv, int Nn, int npad)
{
    int t = threadIdx.x, lane = t & 63, wv = t >> 6;
    int v = blockIdx.x * 4 + wv;
    if (v >= npad) return;
    int sl = lane & 31, half = lane >> 5;

    float4 d4 = {0.f, 0.f, 0.f, 0.f};
    int deg = 0, rs = 0;
    if (v < Nn){
        rs = rowst[v]; deg = rowst[v + 1] - rs;
        d4 = ent4[(size_t)v * 32 + sl];
    }
    float m0 = -1e30f, m1 = -1e30f, m2 = -1e30f;
    float si0 = 0, si1 = 0, si2 = 0, so0 = 0, so1 = 0, so2 = 0;
    float4 aI0 = {0,0,0,0}, aO0 = {0,0,0,0};
    float4 aI1 = {0,0,0,0}, aO1 = {0,0,0,0};
    float4 aI2 = {0,0,0,0}, aO2 = {0,0,0,0};

    for (int base = 0; base < deg; base += 64){
        int nb = min(64, deg - base);
        uint32_t pk = 0;
        if (lane < nb) pk = epack[rs + base + lane];
        int npair = (nb + 1) >> 1;
        // prologue: load pair 0 (pad slots read row 0 — valid memory, zero weight)
        uint32_t w = (uint32_t)__shfl((int)pk, half);
        float4 s4 = ent4[(size_t)(w >> 16) * 32 + sl];
        float4 r4 = rel4[(size_t)((w >> 1) & 0x7FFF) * 32 + sl];
        float mk = (float)(w & 1u);
        bool pad = (half >= nb);
        for (int j = 0; j < npair; ++j){
            // issue next pair's gathers before the dependent softmax chain
            float4 s4n = s4, r4n = r4; float mkn = 0.f; bool padn = true;
            if (j + 1 < npair){
                int ein = 2 * (j + 1) + half;
                uint32_t wn = (uint32_t)__shfl((int)pk, ein);
                s4n = ent4[(size_t)(wn >> 16) * 32 + sl];
                r4n = rel4[(size_t)((wn >> 1) & 0x7FFF) * 32 + sl];
                mkn = (float)(wn & 1u);
                padn = (ein >= nb);
            }
            float4 c4 = { s4.x*r4.x, s4.y*r4.y, s4.z*r4.z, s4.w*r4.w };
            float p0 = r4.x*d4.x + r4.y*d4.y + r4.z*d4.z + r4.w*d4.w;
            float p1 = s4.x*d4.x + s4.y*d4.y + s4.z*d4.z + s4.w*d4.w;
            float p2 = c4.x*d4.x + c4.y*d4.y + c4.z*d4.z + c4.w*d4.w;
            #pragma unroll
            for (int o = 1; o < 32; o <<= 1){
                p0 += __shfl_xor(p0, o);
                p1 += __shfl_xor(p1, o);
                p2 += __shfl_xor(p2, o);
            }
            if (pad){ p0 = -1e38f; p1 = -1e38f; p2 = -1e38f; }
            // layer 0 (message = rel row)
            {
                if (__any(p0 > m0 + 20.f)){
                    float nm = fmaxf(m0, p0);
                    float f = __expf(m0 - nm);
                    si0 *= f; so0 *= f;
                    aI0.x*=f; aI0.y*=f; aI0.z*=f; aI0.w*=f;
                    aO0.x*=f; aO0.y*=f; aO0.z*=f; aO0.w*=f;
                    m0 = nm;
                }
                float e = __expf(p0 - m0);
                float ein_ = e * mk, eout = e - ein_;
                si0 += ein_; so0 += eout;
                aI0.x += ein_*r4.x; aI0.y += ein_*r4.y; aI0.z += ein_*r4.z; aI0.w += ein_*r4.w;
                aO0.x += eout*r4.x; aO0.y += eout*r4.y; aO0.z += eout*r4.z; aO0.w += eout*r4.w;
            }
            // layer 1 (message = src row)
            {
                if (__any(p1 > m1 + 20.f)){
                    float nm = fmaxf(m1, p1);
                    float f = __expf(m1 - nm);
                    si1 *= f; so1 *= f;
                    aI1.x*=f; aI1.y*=f; aI1.z*=f; aI1.w*=f;
                    aO1.x*=f; aO1.y*=f; aO1.z*=f; aO1.w*=f;
                    m1 = nm;
                }
                float e = __expf(p1 - m1);
                float ein_ = e * mk, eout = e - ein_;
                si1 += ein_; so1 += eout;
                aI1.x += ein_*s4.x; aI1.y += ein_*s4.y; aI1.z += ein_*s4.z; aI1.w += ein_*s4.w;
                aO1.x += eout*s4.x; aO1.y += eout*s4.y; aO1.z += eout*s4.z; aO1.w += eout*s4.w;
            }
            // layer 2 (message = src*rel row)
            {
                if (__any(p2 > m2 + 20.f)){
                    float nm = fmaxf(m2, p2);
                    float f = __expf(m2 - nm);
                    si2 *= f; so2 *= f;
                    aI2.x*=f; aI2.y*=f; aI2.z*=f; aI2.w*=f;
                    aO2.x*=f; aO2.y*=f; aO2.z*=f; aO2.w*=f;
                    m2 = nm;
                }
                float e = __expf(p2 - m2);
                float ein_ = e * mk, eout = e - ein_;
                si2 += ein_; so2 += eout;
                aI2.x += ein_*c4.x; aI2.y += ein_*c4.y; aI2.z += ein_*c4.z; aI2.w += ein_*c4.w;
                aO2.x += eout*c4.x; aO2.y += eout*c4.y; aO2.z += eout*c4.z; aO2.w += eout*c4.w;
            }
            s4 = s4n; r4 = r4n; mk = mkn; pad = padn;
        }
    }

    // merge the two half-streams (flash-style rescale to common max)
    {
        float mo, nm, f;
#define MRG(m, si, so, aI, aO)                                            \
        mo = __shfl_xor(m, 32);                                           \
        nm = fmaxf(m, mo);                                                \
        f = __expf(m - nm);                                               \
        si *= f; so *= f;                                                 \
        aI.x*=f; aI.y*=f; aI.z*=f; aI.w*=f;                               \
        aO.x*=f; aO.y*=f; aO.z*=f; aO.w*=f;                               \
        si += __shfl_xor(si, 32);                                         \
        so += __shfl_xor(so, 32);                                         \
        aI.x += __shfl_xor(aI.x, 32); aI.y += __shfl_xor(aI.y, 32);       \
        aI.z += __shfl_xor(aI.z, 32); aI.w += __shfl_xor(aI.w, 32);       \
        aO.x += __shfl_xor(aO.x, 32); aO.y += __shfl_xor(aO.y, 32);       \
        aO.z += __shfl_xor(aO.z, 32); aO.w += __shfl_xor(aO.w, 32);
        MRG(m0, si0, so0, aI0, aO0)
        MRG(m1, si1, so1, aI1, aO1)
        MRG(m2, si2, so2, aI2, aO2)
#undef MRG
    }

    if (half == 0){
        uint2* S2 = (uint2*)Sw;
        size_t s2 = (size_t)npad * 32;
        size_t wi = (size_t)v * 32 + sl;
        float st, inv;
        st = si0 + so0; inv = st > 0.f ? 1.f / st : 0.f;
        S2[0*s2 + wi] = make_uint2(packbf(aI0.x*inv, aI0.y*inv), packbf(aI0.z*inv, aI0.w*inv));
        S2[1*s2 + wi] = make_uint2(packbf(aO0.x*inv, aO0.y*inv), packbf(aO0.z*inv, aO0.w*inv));
        float ri0 = si0*inv, ro0 = so0*inv;
        st = si1 + so1; inv = st > 0.f ? 1.f / st : 0.f;
        S2[2*s2 + wi] = make_uint2(packbf(aI1.x*inv, aI1.y*inv), packbf(aI1.z*inv, aI1.w*inv));
        S2[3*s2 + wi] = make_uint2(packbf(aO1.x*inv, aO1.y*inv), packbf(aO1.z*inv, aO1.w*inv));
        float ri1 = si1*inv, ro1 = so1*inv;
        st = si2 + so2; inv = st > 0.f ? 1.f / st : 0.f;
        S2[4*s2 + wi] = make_uint2(packbf(aI2.x*inv, aI2.y*inv), packbf(aI2.z*inv, aI2.w*inv));
        S2[5*s2 + wi] = make_uint2(packbf(aO2.x*inv, aO2.y*inv), packbf(aO2.z*inv, aO2.w*inv));
        float ri2 = si2*inv, ro2 = so2*inv;
        if (sl == 0){
            Rv[0*(size_t)npad + v] = ri0; Rv[1*(size_t)npad + v] = ro0;
            Rv[2*(size_t)npad + v] = ri1; Rv[3*(size_t)npad + v] = ro1;
            Rv[4*(size_t)npad + v] = ri2; Rv[5*(size_t)npad + v] = ro2;
        }
    }
}

// ---- dense [N x 128] @ W^T GEMM (MFMA) + bias + col stats -----------------
struct GArgs {
    const short* Wi[3]; const short* Wo[3];
    const float* bi[3]; const float* bo[3];
};

__global__ __launch_bounds__(256, 1)
void k_gemm(GArgs ga, const short* Sb, const float* Rv, unsigned short* P,
            float* statsP, int npad, int Nn)
{
    __shared__ float lsum[128], lsq[128];
    int t = threadIdx.x;
    if (t < 128){ lsum[t] = 0.f; lsq[t] = 0.f; }
    __syncthreads();
    int l = blockIdx.y;
    int lane = t & 63, wv = t >> 6;
    int lo = lane & 15, hi = lane >> 4;
    int wr0 = blockIdx.x * 256 + wv * 64;      // wave's 64 rows
    size_t sstride = (size_t)npad * DN;
    const short* Sin  = Sb + (size_t)(2*l)   * sstride;
    const short* Sout = Sb + (size_t)(2*l+1) * sstride;
    const short* Wi = ga.Wi[l]; const short* Wo = ga.Wo[l];

    s16x8 ain[4][4], aout[4][4];               // [row-tile][kb]
    #pragma unroll
    for (int rt = 0; rt < 4; ++rt)
        #pragma unroll
        for (int kb = 0; kb < 4; ++kb){
            size_t o = (size_t)(wr0 + rt*16 + lo) * DN + kb*32 + hi*8;
            ain[rt][kb]  = *(const s16x8*)(Sin + o);
            aout[rt][kb] = *(const s16x8*)(Sout + o);
        }
    float rin[4][4], rout[4][4];
    const float* RvI = Rv + (size_t)(2*l)   * npad;
    const float* RvO = Rv + (size_t)(2*l+1) * npad;
    #pragma unroll
    for (int rt = 0; rt < 4; ++rt)
        #pragma unroll
        for (int rg = 0; rg < 4; ++rg){
            int vr = wr0 + rt*16 + hi*4 + rg;
            rin[rt][rg] = RvI[vr]; rout[rt][rg] = RvO[vr];
        }
    unsigned short* Pl = P + (size_t)l * sstride;

    #pragma unroll
    for (int ct = 0; ct < 8; ++ct){
        s16x8 bwi[4], bwo[4];
        #pragma unroll
        for (int kb = 0; kb < 4; ++kb){
            size_t wo_ = (size_t)(ct*16 + lo) * DN + kb*32 + hi*8;
            bwi[kb] = *(const s16x8*)(Wi + wo_);
            bwo[kb] = *(const s16x8*)(Wo + wo_);
        }
        int j = ct*16 + lo;
        float biv = ga.bi[l][j], bov = ga.bo[l][j];
        float cs = 0.f, cq = 0.f;
        #pragma unroll
        for (int rt = 0; rt < 4; ++rt){
            f32x4 acc = {0.f, 0.f, 0.f, 0.f};
            #pragma unroll
            for (int kb = 0; kb < 4; ++kb){
                acc = __builtin_amdgcn_mfma_f32_16x16x32_bf16(ain[rt][kb], bwi[kb], acc, 0, 0, 0);
                acc = __builtin_amdgcn_mfma_f32_16x16x32_bf16(aout[rt][kb], bwo[kb], acc, 0, 0, 0);
            }
            #pragma unroll
            for (int rg = 0; rg < 4; ++rg){
                float pv = acc[rg] + rin[rt][rg]*biv + rout[rt][rg]*bov;
                Pl[(size_t)(wr0 + rt*16 + hi*4 + rg) * DN + j] = (unsigned short)f2bf(pv);
                cs += pv; cq += pv*pv;
            }
        }
        cs += __shfl_xor(cs, 16); cs += __shfl_xor(cs, 32);
        cq += __shfl_xor(cq, 16); cq += __shfl_xor(cq, 32);
        if (lane < 16){ atomicAdd(&lsum[j], cs); atomicAdd(&lsq[j], cq); }
    }
    __syncthreads();
    float* stats = statsP + (size_t)((blockIdx.x ^ (blockIdx.y << 4)) & (NSTAT-1)) * 768;
    if (t < 128){
        atomicAdd(&stats[l*128 + t], lsum[t]);
        atomicAdd(&stats[384 + l*128 + t], lsq[t]);
    }
}

// ---- reduce stat partials -> BN constants A,B -----------------------------
struct BArgs { const float* g[3]; const float* b[3]; };

__global__ void k_bn(BArgs ba, const float* statsP, float* bnAB, int Nn){
    int t = threadIdx.x;
    if (t >= 384) return;
    float su = 0.f, sq = 0.f;
    for (int k = 0; k < NSTAT; ++k){
        su += statsP[(size_t)k * 768 + t];
        sq += statsP[(size_t)k * 768 + 384 + t];
    }
    int l = t >> 7;
    float mu = su / (float)Nn;
    float var = fmaxf(sq / (float)Nn - mu*mu, 0.f);
    float inv = rsqrtf(var + 1e-5f);
    float g = ba.g[l][t & 127], b = ba.b[l][t & 127];
    bnAB[t] = g * inv;
    bnAB[384 + t] = b - mu * g * inv;
}

// ---- fused final: ent output | relation update ----------------------------
__global__ __launch_bounds__(256)
void k_fin(const unsigned short* Pb, const float* bnAB,
           const float* ent, const float* relW, const float* relb,
           const float* rel, const int* heads, const int* tails,
           float* outp, int Nn, int npad, int FB, int Sp)
{
    int t = threadIdx.x, bid = blockIdx.x;
    if (bid < FB){
        __shared__ float sAB[768];
        for (int i = t; i < 768; i += 256) sAB[i] = bnAB[i];
        __syncthreads();
        int gid = bid * 256 + t;
        if (gid >= Nn * 32) return;
        int v = gid >> 5, q4 = (gid & 31) * 4;
        size_t pst = (size_t)npad * DN;
        size_t pb = (size_t)v * DN + q4;
        ushort4 p0 = *(const ushort4*)(Pb + pb);
        ushort4 p1 = *(const ushort4*)(Pb + pst + pb);
        ushort4 p2 = *(const ushort4*)(Pb + 2*pst + pb);
        float4 e4 = *(const float4*)(ent + (size_t)v * DN + q4);
        float pe[4] = { e4.x, e4.y, e4.z, e4.w };
        unsigned short pu[3][4] = { {p0.x, p0.y, p0.z, p0.w},
                                    {p1.x, p1.y, p1.z, p1.w},
                                    {p2.x, p2.y, p2.z, p2.w} };
        float o[4];
        #pragma unroll
        for (int q = 0; q < 4; ++q){
            float s = pe[q];
            #pragma unroll
            for (int l = 0; l < 3; ++l){
                int jj = l*128 + q4 + q;
                s += tanh_(sAB[jj] * bfs(pu[l][q]) + sAB[384 + jj]);
            }
            o[q] = s;
        }
        float4 ov = { o[0], o[1], o[2], o[3] };
        *(float4*)(outp + (size_t)v * DN + q4) = ov;
    } else {
        __shared__ float mp[256];
        int rr = (bid - FB) * 2 + (t >> 7);
        int j = t & 127;
        float acc = 0.f;
        for (int s = 0; s < Sp; ++s){
            int p = rr * Sp + s;
            acc += ent[(size_t)tails[p] * DN + j] - ent[(size_t)heads[p] * DN + j];
        }
        mp[t] = acc / (float)Sp;
        __syncthreads();
        float dot = relb[j];
        const float4* wr = (const float4*)(relW + (size_t)j * DN);
        const float* mpr = mp + (t >> 7) * 128;
        #pragma unroll 8
        for (int kb = 0; kb < 32; ++kb){
            float4 w = wr[kb];
            dot += mpr[kb*4+0]*w.x + mpr[kb*4+1]*w.y + mpr[kb*4+2]*w.z + mpr[kb*4+3]*w.w;
        }
        outp[(size_t)Nn * DN + (size_t)rr * DN + j] = rel[(size_t)rr * DN + j] + tanh_(dot);
    }
}

// ---------------------------------------------------------------------------
extern "C" void kernel_launch(void* const* d_in, const int* in_sizes, int n_in,
                              void* d_out, int out_size, void* d_ws, size_t ws_size,
                              hipStream_t stream)
{
    const float* entf = (const float*)d_in[0];
    const float* relf = (const float*)d_in[1];
    const float* eWo = (const float*)d_in[2];  const float* ebo = (const float*)d_in[3];
    const float* eWi = (const float*)d_in[4];  const float* ebi = (const float*)d_in[5];
    const float* eg  = (const float*)d_in[6];  const float* eb  = (const float*)d_in[7];
    const float* nWo = (const float*)d_in[8];  const float* nbo = (const float*)d_in[9];
    const float* nWi = (const float*)d_in[10]; const float* nbi = (const float*)d_in[11];
    const float* ng  = (const float*)d_in[12]; const float* nb_ = (const float*)d_in[13];
    const float* cWo = (const float*)d_in[14]; const float* cbo = (const float*)d_in[15];
    const float* cWi = (const float*)d_in[16]; const float* cbi = (const float*)d_in[17];
    const float* cg  = (const float*)d_in[18]; const float* cb  = (const float*)d_in[19];
    const float* relWs  = (const float*)d_in[20];
    const float* relb32 = (const float*)d_in[21];
    const int* srcp   = (const int*)d_in[22];
    const int* dstp   = (const int*)d_in[23];
    const int* etyp   = (const int*)d_in[24];
    const int* headsp = (const int*)d_in[25];
    const int* tailsp = (const int*)d_in[26];
    const unsigned char* mask8 = (const unsigned char*)d_in[28];   // in_mask

    int Nn = in_sizes[0] / DN;
    int Rr = in_sizes[1] / DN;
    int E  = in_sizes[22];
    int Pp = in_sizes[25];
    int Sp = Pp / Rr;
    int npad = ((Nn + 255) / 256) * 256;
    int nsb = npad / 256;

    char* w = (char*)d_ws; size_t off = 0;
    auto carve = [&](size_t b) -> void* {
        void* p = w + off; off = (off + b + 255) & ~(size_t)255; return p;
    };
    // zero-region first (flag | counts | statsP), one memset covers all
    int*   flag   = (int*)  carve(4);
    int*   counts = (int*)  carve((size_t)npad * 4);
    float* statsP = (float*)carve((size_t)NSTAT * 768 * 4);
    size_t zlen = off;
    int*   rowst  = (int*)  carve((size_t)(npad + 1) * 4);
    int*   cursor = (int*)  carve((size_t)npad * 4);
    uint32_t* epack = (uint32_t*)carve((size_t)E * 4);
    int*   bsums  = (int*)  carve(1024 * 4);
    unsigned short* wcv = (unsigned short*)carve((size_t)6 * 16384 * 2);
    short* Sb     = (short*)carve((size_t)6 * npad * DN * 2);
    unsigned short* Pb = (unsigned short*)carve((size_t)3 * npad * DN * 2);
    float* Rv     = (float*)carve((size_t)6 * npad * 4);
    float* bnAB   = (float*)carve(768 * 4);

    hipMemsetAsync(d_ws, 0, zlen, stream);

    WC wc; wc.src[0] = eWi; wc.src[1] = nWi; wc.src[2] = cWi;
           wc.src[3] = eWo; wc.src[4] = nWo; wc.src[5] = cWo;
    int nwords = 4096;
    k_pre<<<(E + 255) / 256, 256, 0, stream>>>(dstp, counts, (const uint32_t*)mask8,
                                               nwords, flag, wc, wcv, E);
    k_scan_a<<<nsb, 256, 0, stream>>>(counts, bsums);
    k_scan_bc<<<nsb, 256, 0, stream>>>(counts, bsums, nsb, rowst, cursor, npad, E);
    k_scatter<<<(E + 255) / 256, 256, 0, stream>>>(dstp, srcp, etyp, mask8, flag,
                                                   cursor, epack, E);

    k_node<<<npad / 4, 256, 0, stream>>>((const float4*)entf, (const float4*)relf,
                                         epack, rowst, (uint32_t*)Sb, Rv, Nn, npad);

    GArgs ga;
    ga.Wi[0] = (const short*)(wcv + 0*16384);
    ga.Wi[1] = (const short*)(wcv + 1*16384);
    ga.Wi[2] = (const short*)(wcv + 2*16384);
    ga.Wo[0] = (const short*)(wcv + 3*16384);
    ga.Wo[1] = (const short*)(wcv + 4*16384);
    ga.Wo[2] = (const short*)(wcv + 5*16384);
    ga.bi[0] = ebi; ga.bi[1] = nbi; ga.bi[2] = cbi;
    ga.bo[0] = ebo; ga.bo[1] = nbo; ga.bo[2] = cbo;
    k_gemm<<<dim3(npad / 256, 3), 256, 0, stream>>>(ga, Sb, Rv, Pb, statsP, npad, Nn);

    BArgs ba;
    ba.g[0] = eg; ba.g[1] = ng; ba.g[2] = cg;
    ba.b[0] = eb; ba.b[1] = nb_; ba.b[2] = cb;
    k_bn<<<1, 384, 0, stream>>>(ba, statsP, bnAB, Nn);

    int FB = (Nn * 32 + 255) / 256;
    int grid = FB + Rr / 2;
    k_fin<<<grid, 256, 0, stream>>>(Pb, bnAB, entf, relWs, relb32, relf,
                                    headsp, tailsp, (float*)d_out, Nn, npad, FB, Sp);
}